// Round 6
// baseline (4291.241 us; speedup 1.0000x reference)
//
#include <hip/hip_runtime.h>

#define DDIM 128
#define HDIM 256
#define BQ   4
#define NN   4096
#define RTOT (BQ*NN)

typedef short short8 __attribute__((ext_vector_type(8)));
typedef float f32x16 __attribute__((ext_vector_type(16)));

__device__ inline unsigned short f2bf(float f) {
    unsigned int u = __float_as_uint(f);
    unsigned int r = (u + 0x7fffu + ((u >> 16) & 1u)) >> 16;
    return (unsigned short)r;
}
__device__ inline float bf2f(unsigned short h) {
    return __uint_as_float(((unsigned int)h) << 16);
}

// ---------------- fused sim (K K^T, split-bf16 MFMA, swapped operands) + per-row top-8 ----
// grid 256 (1 block/CU), block 256 = 4 waves. Block = 128 rows x 2048 cols (col-half ch).
// Wave w owns rows rowbase+w*32..+32 (A in regs/AGPRs, round-5 layout). All 4 waves consume
// the SAME staged B cols (x4 LDS reuse). B staged via global_load_lds w16 into
// [plane][seg][col*16B] (linear dest, conflict-free reads), triple buffer, 2-step prefetch,
// per-wave vmcnt(4) BEFORE the single per-step barrier (DMA-race-safe protocol).
// Output = sim^T: per-row top-8 lane-local; 4 partial lists/row merged in gather kernel.
__global__ __launch_bounds__(256, 1)
void sim_topk_kernel(const unsigned short* __restrict__ khi,
                     const unsigned short* __restrict__ klo,
                     float* __restrict__ svals, int* __restrict__ sidxb) {
    __shared__ char smem[3 * 16384];

    const int id = blockIdx.x;
    const int xcd = id & 7;
    const int b = xcd >> 1;                       // batch -> XCD pair (L2 residency)
    const int j = ((id >> 3) << 1) | (xcd & 1);   // 0..63
    const int rowgroup = j >> 1;                  // 0..31
    const int ch = j & 1;                         // col half
    const int rowbase = rowgroup * 128;
    const int colbase = ch * 2048;
    const unsigned short* khiB = khi + (size_t)b * NN * HDIM;
    const unsigned short* kloB = klo + (size_t)b * NN * HDIM;

    const int tid = threadIdx.x;
    const int lane = tid & 63, w = tid >> 6;
    const int l31 = lane & 31, lh = lane >> 5;

    // ---- A: this wave's 32 rows (hi+lo), full K=256, in regs (round-5 proven layout) ----
    const int myrow = rowbase + w * 32 + l31;
    short8 ah[16], al[16];
    {
        const unsigned short* ph = khiB + (size_t)myrow * HDIM + lh * 8;
        const unsigned short* pl = kloB + (size_t)myrow * HDIM + lh * 8;
#pragma unroll
        for (int T = 0; T < 16; ++T) {
            ah[T] = *(const short8*)(ph + T * 16);
            al[T] = *(const short8*)(pl + T * 16);
        }
    }
#pragma unroll
    for (int T = 0; T < 16; ++T) {
        asm volatile("" : "+v"(ah[T]));
        asm volatile("" : "+v"(al[T]));
    }

    // ---- staging: step s = (g, kb) stages 128 cols x 32 k x 2 planes = 16 KB into buf s%3 ----
    // unit u = w*4+i: p=u>>3, seg=(u>>1)&3, c64=u&1. Dest = uniform base (+ lane*16 by HW).
    // Source col = colbase + g*128 + c64*64 + lane, k = kb*32 + seg*8 (16B).
    auto stage = [&](int s) {
        const int g2 = s >> 3, kb2 = s & 7;
        char* bufb = smem + (s % 3) * 16384;
#pragma unroll
        for (int i = 0; i < 4; ++i) {
            const int u = w * 4 + i;
            const int p = u >> 3, seg = (u >> 1) & 3, c64 = u & 1;
            const int col = colbase + g2 * 128 + c64 * 64 + lane;
            const unsigned short* src = (p ? kloB : khiB) + (size_t)col * HDIM + kb2 * 32 + seg * 8;
            __builtin_amdgcn_global_load_lds(
                (const __attribute__((address_space(1))) void*)src,
                (__attribute__((address_space(3))) void*)(bufb + p * 8192 + seg * 2048 + c64 * 1024),
                16, 0, 0);
        }
    };

    stage(0);
    stage(1);

    float tv[8]; int ti[8];
#pragma unroll
    for (int s = 0; s < 8; ++s) { tv[s] = -1e30f; ti[s] = 0x7fffffff; }

    auto scan_frag = [&](const f32x16& acc, int cbf) {
#pragma unroll
        for (int r = 0; r < 16; ++r) {
            float v = acc[r];
            int col = cbf + (r & 3) + 8 * (r >> 2);
            if (v > tv[7]) {
                tv[7] = v; ti[7] = col;
#pragma unroll
                for (int q = 7; q >= 1; --q) {
                    if (tv[q] > tv[q - 1]) {
                        float a0 = tv[q]; tv[q] = tv[q - 1]; tv[q - 1] = a0;
                        int   c0 = ti[q]; ti[q] = ti[q - 1]; ti[q - 1] = c0;
                    }
                }
            }
        }
    };

    for (int g = 0; g < 16; ++g) {
        f32x16 acc0, acc1, acc2, acc3;
#pragma unroll
        for (int r = 0; r < 16; ++r) { acc0[r] = 0.f; acc1[r] = 0.f; acc2[r] = 0.f; acc3[r] = 0.f; }

#pragma unroll
        for (int kb = 0; kb < 8; ++kb) {
            const int s = g * 8 + kb;
            // per-wave: own step-s loads landed; barrier makes it block-wide (race-safe)
            if (s < 127) asm volatile("s_waitcnt vmcnt(4)" ::: "memory");
            else         asm volatile("s_waitcnt vmcnt(0)" ::: "memory");
            __builtin_amdgcn_s_barrier();
            if (s + 2 < 128) stage(s + 2);   // clobbers buf (s-1)%3: all waves done reading it

            const char* bb = smem + (s % 3) * 16384;
#pragma unroll
            for (int ks = 0; ks < 2; ++ks) {
                const int T = kb * 2 + ks;
                const char* segp = bb + (ks * 2 + lh) * 2048 + l31 * 16;
                short8 bh0 = *(const short8*)(segp);
                short8 bl0 = *(const short8*)(segp + 8192);
                acc0 = __builtin_amdgcn_mfma_f32_32x32x16_bf16(bh0, ah[T], acc0, 0, 0, 0);
                acc0 = __builtin_amdgcn_mfma_f32_32x32x16_bf16(bh0, al[T], acc0, 0, 0, 0);
                acc0 = __builtin_amdgcn_mfma_f32_32x32x16_bf16(bl0, ah[T], acc0, 0, 0, 0);
                short8 bh1 = *(const short8*)(segp + 512);
                short8 bl1 = *(const short8*)(segp + 8192 + 512);
                acc1 = __builtin_amdgcn_mfma_f32_32x32x16_bf16(bh1, ah[T], acc1, 0, 0, 0);
                acc1 = __builtin_amdgcn_mfma_f32_32x32x16_bf16(bh1, al[T], acc1, 0, 0, 0);
                acc1 = __builtin_amdgcn_mfma_f32_32x32x16_bf16(bl1, ah[T], acc1, 0, 0, 0);
                short8 bh2 = *(const short8*)(segp + 1024);
                short8 bl2 = *(const short8*)(segp + 8192 + 1024);
                acc2 = __builtin_amdgcn_mfma_f32_32x32x16_bf16(bh2, ah[T], acc2, 0, 0, 0);
                acc2 = __builtin_amdgcn_mfma_f32_32x32x16_bf16(bh2, al[T], acc2, 0, 0, 0);
                acc2 = __builtin_amdgcn_mfma_f32_32x32x16_bf16(bl2, ah[T], acc2, 0, 0, 0);
                short8 bh3 = *(const short8*)(segp + 1536);
                short8 bl3 = *(const short8*)(segp + 8192 + 1536);
                acc3 = __builtin_amdgcn_mfma_f32_32x32x16_bf16(bh3, ah[T], acc3, 0, 0, 0);
                acc3 = __builtin_amdgcn_mfma_f32_32x32x16_bf16(bh3, al[T], acc3, 0, 0, 0);
                acc3 = __builtin_amdgcn_mfma_f32_32x32x16_bf16(bl3, ah[T], acc3, 0, 0, 0);
            }
        }

        // scan 64 lane-local sim values (ascending col; strict > = ref tie semantics)
        const int cb0 = colbase + g * 128 + 4 * lh;
        scan_frag(acc0, cb0);
        scan_frag(acc1, cb0 + 32);
        scan_frag(acc2, cb0 + 64);
        scan_frag(acc3, cb0 + 96);
    }

    // ---- write this lane's partial list: list = (ch, lh) of row myrow ----
    const size_t row = (size_t)b * NN + myrow;
    const size_t lbase = ((row * 2 + ch) * 2 + lh) * 8;
#pragma unroll
    for (int s = 0; s < 8; ++s) { svals[lbase + s] = tv[s]; sidxb[lbase + s] = ti[s]; }
}

// ---------------- keys projection GEMM + fused normalize -> khi/klo (bf16 planes) ----------------
__global__ __launch_bounds__(256, 2)
void gemm_keys(const float* __restrict__ A, const float* __restrict__ W,
               const float* __restrict__ bias,
               unsigned short* __restrict__ khi, unsigned short* __restrict__ klo) {
    __shared__ float As[32 * 132];
    int tid = threadIdx.x;
    size_t rowbase = (size_t)blockIdx.x * 32;
    for (int i = tid; i < 32 * 32; i += 256) {
        int r = i >> 5, q = i & 31;
        *(float4*)&As[r * 132 + q * 4] = *(const float4*)&A[(rowbase + r) * DDIM + q * 4];
    }
    __syncthreads();
    int rg = tid >> 5, cg = tid & 31;
    int r0 = rg * 4, c0 = cg * 8;
    float acc[4][8];
#pragma unroll
    for (int i = 0; i < 4; ++i)
#pragma unroll
        for (int j = 0; j < 8; ++j) acc[i][j] = 0.f;

#pragma unroll 2
    for (int k = 0; k < DDIM; k += 4) {
        float a[4][4];
#pragma unroll
        for (int i = 0; i < 4; ++i) {
            float4 t = *(const float4*)&As[(r0 + i) * 132 + k];
            a[i][0] = t.x; a[i][1] = t.y; a[i][2] = t.z; a[i][3] = t.w;
        }
#pragma unroll
        for (int kk = 0; kk < 4; ++kk) {
            float4 w0 = *(const float4*)&W[(size_t)(k + kk) * HDIM + c0];
            float4 w1 = *(const float4*)&W[(size_t)(k + kk) * HDIM + c0 + 4];
            float wv[8] = {w0.x, w0.y, w0.z, w0.w, w1.x, w1.y, w1.z, w1.w};
#pragma unroll
            for (int i = 0; i < 4; ++i)
#pragma unroll
                for (int j = 0; j < 8; ++j) acc[i][j] += a[i][kk] * wv[j];
        }
    }
    float4 bz0 = *(const float4*)&bias[c0];
    float4 bz1 = *(const float4*)&bias[c0 + 4];
    float bz[8] = {bz0.x, bz0.y, bz0.z, bz0.w, bz1.x, bz1.y, bz1.z, bz1.w};
#pragma unroll
    for (int i = 0; i < 4; ++i) {
        float vv[8];
        float ss = 0.f;
#pragma unroll
        for (int j = 0; j < 8; ++j) { vv[j] = acc[i][j] + bz[j]; ss += vv[j]*vv[j]; }
#pragma unroll
        for (int m = 16; m; m >>= 1) ss += __shfl_xor(ss, m);
        float sc = 1.0f / fmaxf(sqrtf(ss), 1e-12f);
        short8 hv, lv;
#pragma unroll
        for (int j = 0; j < 8; ++j) {
            float vn = vv[j] * sc;
            unsigned short h = f2bf(vn);
            hv[j] = (short)h;
            lv[j] = (short)f2bf(vn - bf2f(h));
        }
        *(short8*)&khi[(rowbase + r0 + i) * HDIM + c0] = hv;
        *(short8*)&klo[(rowbase + r0 + i) * HDIM + c0] = lv;
    }
}

// ---------------- agg projection GEMM: out = A(Rx128) @ W(128x256) + bias ----------------
__global__ __launch_bounds__(256, 2)
void gemm_d_h(const float* __restrict__ A, const float* __restrict__ W,
              const float* __restrict__ bias, float* __restrict__ out) {
    __shared__ float As[32 * 132];
    int tid = threadIdx.x;
    size_t rowbase = (size_t)blockIdx.x * 32;
    for (int i = tid; i < 32 * 32; i += 256) {
        int r = i >> 5, q = i & 31;
        *(float4*)&As[r * 132 + q * 4] = *(const float4*)&A[(rowbase + r) * DDIM + q * 4];
    }
    __syncthreads();
    int rg = tid >> 5, cg = tid & 31;
    int r0 = rg * 4, c0 = cg * 8;
    float acc[4][8];
#pragma unroll
    for (int i = 0; i < 4; ++i)
#pragma unroll
        for (int j = 0; j < 8; ++j) acc[i][j] = 0.f;

#pragma unroll 2
    for (int k = 0; k < DDIM; k += 4) {
        float a[4][4];
#pragma unroll
        for (int i = 0; i < 4; ++i) {
            float4 t = *(const float4*)&As[(r0 + i) * 132 + k];
            a[i][0] = t.x; a[i][1] = t.y; a[i][2] = t.z; a[i][3] = t.w;
        }
#pragma unroll
        for (int kk = 0; kk < 4; ++kk) {
            float4 w0 = *(const float4*)&W[(size_t)(k + kk) * HDIM + c0];
            float4 w1 = *(const float4*)&W[(size_t)(k + kk) * HDIM + c0 + 4];
            float wv[8] = {w0.x, w0.y, w0.z, w0.w, w1.x, w1.y, w1.z, w1.w};
#pragma unroll
            for (int i = 0; i < 4; ++i)
#pragma unroll
                for (int j = 0; j < 8; ++j) acc[i][j] += a[i][kk] * wv[j];
        }
    }
    float4 bz0 = *(const float4*)&bias[c0];
    float4 bz1 = *(const float4*)&bias[c0 + 4];
    float bz[8] = {bz0.x, bz0.y, bz0.z, bz0.w, bz1.x, bz1.y, bz1.z, bz1.w};
#pragma unroll
    for (int i = 0; i < 4; ++i) {
        float4 o0, o1;
        o0.x = acc[i][0] + bz[0]; o0.y = acc[i][1] + bz[1]; o0.z = acc[i][2] + bz[2]; o0.w = acc[i][3] + bz[3];
        o1.x = acc[i][4] + bz[4]; o1.y = acc[i][5] + bz[5]; o1.z = acc[i][6] + bz[6]; o1.w = acc[i][7] + bz[7];
        *(float4*)&out[(rowbase + r0 + i) * HDIM + c0] = o0;
        *(float4*)&out[(rowbase + r0 + i) * HDIM + c0 + 4] = o1;
    }
}

// ---------------- merge 4 partial lists/row (wave-parallel argmax) + gather + mean ----------------
// 4 rows/block; wave w merges row row0+w's 32 entries via shfl argmax (exact lexicographic).
__global__ void gather_mean_kernel(const float* __restrict__ state,
                                   const float* __restrict__ svals, const int* __restrict__ sidxb,
                                   float* __restrict__ M) {
    __shared__ int ilds[4][8];
    int tid = threadIdx.x;
    int lane = tid & 63, w = tid >> 6;
    int row0 = blockIdx.x * 4;
    {
        size_t row = (size_t)(row0 + w);
        int e = lane & 31;
        float v = svals[row * 32 + e];
        int  ix = sidxb[row * 32 + e];
#pragma unroll
        for (int s = 0; s < 8; ++s) {
            float mv = v; int mi = ix;
#pragma unroll
            for (int m = 1; m < 32; m <<= 1) {
                float ov = __shfl_xor(mv, m);
                int   oi = __shfl_xor(mi, m);
                if (ov > mv || (ov == mv && oi < mi)) { mv = ov; mi = oi; }
            }
            if (lane == 0) ilds[w][s] = mi;
            if (ix == mi) v = -1e30f;   // indices unique across lists (disjoint col sets)
        }
    }
    __syncthreads();
    for (int o = tid; o < 4 * DDIM; o += 256) {
        int lr = o >> 7, d = o & 127;
        int grow = row0 + lr;
        int bb = grow >> 12;
        const float* sb = state + (size_t)bb * NN * DDIM;
        float acc = 0.f;
#pragma unroll
        for (int k = 0; k < 8; ++k) acc += sb[(size_t)ilds[lr][k] * DDIM + d];
        M[(size_t)grow * DDIM + d] = acc * 0.125f;
    }
}

// ---------------- concat GEMM (K=384) + LayerNorm epilogue ----------------
__global__ __launch_bounds__(256, 2)
void gemm_ln(const float* __restrict__ state, const float* __restrict__ agg,
             const float* __restrict__ W1, const float* __restrict__ b1,
             const float* __restrict__ lng, const float* __restrict__ lnb,
             float* __restrict__ h) {
    __shared__ float As[32 * 388];
    int tid = threadIdx.x;
    size_t rowbase = (size_t)blockIdx.x * 32;
    for (int i = tid; i < 32 * 96; i += 256) {
        int r = i / 96, q = i % 96;
        float4 v;
        if (q < 32) v = *(const float4*)&state[(rowbase + r) * DDIM + q * 4];
        else        v = *(const float4*)&agg[(rowbase + r) * HDIM + (q - 32) * 4];
        *(float4*)&As[r * 388 + q * 4] = v;
    }
    __syncthreads();
    int rg = tid >> 5, cg = tid & 31;
    int r0 = rg * 4, c0 = cg * 8;
    float acc[4][8];
#pragma unroll
    for (int i = 0; i < 4; ++i)
#pragma unroll
        for (int j = 0; j < 8; ++j) acc[i][j] = 0.f;

#pragma unroll 2
    for (int k = 0; k < 384; k += 4) {
        float a[4][4];
#pragma unroll
        for (int i = 0; i < 4; ++i) {
            float4 t = *(const float4*)&As[(r0 + i) * 388 + k];
            a[i][0] = t.x; a[i][1] = t.y; a[i][2] = t.z; a[i][3] = t.w;
        }
#pragma unroll
        for (int kk = 0; kk < 4; ++kk) {
            float4 w0 = *(const float4*)&W1[(size_t)(k + kk) * HDIM + c0];
            float4 w1 = *(const float4*)&W1[(size_t)(k + kk) * HDIM + c0 + 4];
            float wv[8] = {w0.x, w0.y, w0.z, w0.w, w1.x, w1.y, w1.z, w1.w};
#pragma unroll
            for (int i = 0; i < 4; ++i)
#pragma unroll
                for (int j = 0; j < 8; ++j) acc[i][j] += a[i][kk] * wv[j];
        }
    }
    float4 b10 = *(const float4*)&b1[c0];
    float4 b11 = *(const float4*)&b1[c0 + 4];
    float bb[8] = {b10.x, b10.y, b10.z, b10.w, b11.x, b11.y, b11.z, b11.w};
    float4 g0 = *(const float4*)&lng[c0];
    float4 g1 = *(const float4*)&lng[c0 + 4];
    float lg[8] = {g0.x, g0.y, g0.z, g0.w, g1.x, g1.y, g1.z, g1.w};
    float4 e0 = *(const float4*)&lnb[c0];
    float4 e1 = *(const float4*)&lnb[c0 + 4];
    float lb[8] = {e0.x, e0.y, e0.z, e0.w, e1.x, e1.y, e1.z, e1.w};

#pragma unroll
    for (int i = 0; i < 4; ++i) {
        float s1 = 0.f, s2 = 0.f;
#pragma unroll
        for (int j = 0; j < 8; ++j) {
            acc[i][j] += bb[j];
            s1 += acc[i][j];
            s2 += acc[i][j] * acc[i][j];
        }
#pragma unroll
        for (int m = 16; m; m >>= 1) { s1 += __shfl_xor(s1, m); s2 += __shfl_xor(s2, m); }
        float mu = s1 * (1.0f / HDIM);
        float var = s2 * (1.0f / HDIM) - mu * mu;
        float inv = 1.0f / sqrtf(var + 1e-5f);
        float4 o0, o1;
        o0.x = (acc[i][0] - mu) * inv * lg[0] + lb[0];
        o0.y = (acc[i][1] - mu) * inv * lg[1] + lb[1];
        o0.z = (acc[i][2] - mu) * inv * lg[2] + lb[2];
        o0.w = (acc[i][3] - mu) * inv * lg[3] + lb[3];
        o1.x = (acc[i][4] - mu) * inv * lg[4] + lb[4];
        o1.y = (acc[i][5] - mu) * inv * lg[5] + lb[5];
        o1.z = (acc[i][6] - mu) * inv * lg[6] + lb[6];
        o1.w = (acc[i][7] - mu) * inv * lg[7] + lb[7];
        *(float4*)&h[(rowbase + r0 + i) * HDIM + c0] = o0;
        *(float4*)&h[(rowbase + r0 + i) * HDIM + c0 + 4] = o1;
    }
}

// ---------------- update GEMM: state += silu(h) @ W2 + b2 ----------------
__global__ __launch_bounds__(256, 2)
void gemm_upd(const float* __restrict__ h, const float* __restrict__ W2,
              const float* __restrict__ b2, float* __restrict__ state) {
    __shared__ float As[32 * 260];
    int tid = threadIdx.x;
    size_t rowbase = (size_t)blockIdx.x * 32;
    for (int i = tid; i < 32 * 64; i += 256) {
        int r = i >> 6, q = i & 63;
        float4 v = *(const float4*)&h[(rowbase + r) * HDIM + q * 4];
        v.x = v.x / (1.0f + expf(-v.x));
        v.y = v.y / (1.0f + expf(-v.y));
        v.z = v.z / (1.0f + expf(-v.z));
        v.w = v.w / (1.0f + expf(-v.w));
        *(float4*)&As[r * 260 + q * 4] = v;
    }
    __syncthreads();
    int rg = tid >> 4, cg = tid & 15;
    int r0 = rg * 2, c0 = cg * 8;
    float acc[2][8];
#pragma unroll
    for (int i = 0; i < 2; ++i)
#pragma unroll
        for (int j = 0; j < 8; ++j) acc[i][j] = 0.f;

#pragma unroll 2
    for (int k = 0; k < HDIM; k += 4) {
        float a[2][4];
#pragma unroll
        for (int i = 0; i < 2; ++i) {
            float4 t = *(const float4*)&As[(r0 + i) * 260 + k];
            a[i][0] = t.x; a[i][1] = t.y; a[i][2] = t.z; a[i][3] = t.w;
        }
#pragma unroll
        for (int kk = 0; kk < 4; ++kk) {
            float4 w0 = *(const float4*)&W2[(size_t)(k + kk) * DDIM + c0];
            float4 w1 = *(const float4*)&W2[(size_t)(k + kk) * DDIM + c0 + 4];
            float wv[8] = {w0.x, w0.y, w0.z, w0.w, w1.x, w1.y, w1.z, w1.w};
#pragma unroll
            for (int i = 0; i < 2; ++i)
#pragma unroll
                for (int j = 0; j < 8; ++j) acc[i][j] += a[i][kk] * wv[j];
        }
    }
    float4 bz0 = *(const float4*)&b2[c0];
    float4 bz1 = *(const float4*)&b2[c0 + 4];
    float bz[8] = {bz0.x, bz0.y, bz0.z, bz0.w, bz1.x, bz1.y, bz1.z, bz1.w};
#pragma unroll
    for (int i = 0; i < 2; ++i) {
        size_t off = (rowbase + r0 + i) * DDIM + c0;
        float4 s0 = *(const float4*)&state[off];
        float4 s1 = *(const float4*)&state[off + 4];
        s0.x += acc[i][0] + bz[0]; s0.y += acc[i][1] + bz[1];
        s0.z += acc[i][2] + bz[2]; s0.w += acc[i][3] + bz[3];
        s1.x += acc[i][4] + bz[4]; s1.y += acc[i][5] + bz[5];
        s1.z += acc[i][6] + bz[6]; s1.w += acc[i][7] + bz[7];
        *(float4*)&state[off] = s0;
        *(float4*)&state[off + 4] = s1;
    }
}

// ---------------- final: mean over N, then @ Wo + bo ----------------
__global__ void partial_mean_kernel(const float* __restrict__ state, float* __restrict__ partial) {
    int b = blockIdx.y, seg = blockIdx.x, tid = threadIdx.x;  // 128 threads
    const float* sp = state + ((size_t)b * NN + (size_t)seg * 128) * DDIM;
    float acc = 0.f;
    for (int i = 0; i < 128; ++i) acc += sp[(size_t)i * DDIM + tid];
    partial[((size_t)b * 32 + seg) * DDIM + tid] = acc;
}

__global__ void final_out_kernel(const float* __restrict__ partial, const float* __restrict__ Wo,
                                 const float* __restrict__ bo, float* __restrict__ out) {
    __shared__ float mean[BQ][DDIM];
    int tid = threadIdx.x;
    for (int o = tid; o < BQ * DDIM; o += 256) {
        int b = o >> 7, d = o & 127;
        float s = 0.f;
        for (int p = 0; p < 32; ++p) s += partial[((size_t)b * 32 + p) * DDIM + d];
        mean[b][d] = s * (1.0f / NN);
    }
    __syncthreads();
    for (int o = tid; o < BQ * DDIM; o += 256) {
        int b = o >> 7, c = o & 127;
        float acc = bo[c];
        for (int d = 0; d < DDIM; ++d) acc += mean[b][d] * Wo[d * DDIM + c];
        out[o] = acc;
    }
}

extern "C" void kernel_launch(void* const* d_in, const int* in_sizes, int n_in,
                              void* d_out, int out_size, void* d_ws, size_t ws_size,
                              hipStream_t stream) {
    const float* x   = (const float*)d_in[0];
    const float* Wn  = (const float*)d_in[1];
    const float* bn  = (const float*)d_in[2];
    const float* W1  = (const float*)d_in[3];
    const float* b1  = (const float*)d_in[4];
    const float* lng = (const float*)d_in[5];
    const float* lnb = (const float*)d_in[6];
    const float* W2  = (const float*)d_in[7];
    const float* b2  = (const float*)d_in[8];
    const float* Wo  = (const float*)d_in[9];
    const float* bo  = (const float*)d_in[10];
    float* out = (float*)d_out;

    float* ws      = (float*)d_ws;
    float* state   = ws;                                        // R*128 f32
    float* keysagg = state + (size_t)RTOT * DDIM;               // R*256 f32
    float* hbuf    = keysagg + (size_t)RTOT * HDIM;             // R*256 f32
    unsigned short* khi_b = (unsigned short*)hbuf;              // R*256 bf16
    unsigned short* klo_b = khi_b + (size_t)RTOT * HDIM;        // R*256 bf16
    float* Mbuf    = hbuf;                                      // R*128 f32 (after sim)
    float* partial = hbuf + (size_t)RTOT * HDIM;                // B*32*128
    // top-8 partial lists: live only between sim and gather; alias keysagg (dead there)
    float* svals   = keysagg;                                   // R*32 f32
    int*   sidxb   = (int*)(keysagg + (size_t)RTOT * 32);       // R*32 i32

    hipMemcpyAsync(state, x, (size_t)RTOT * DDIM * sizeof(float),
                   hipMemcpyDeviceToDevice, stream);

    for (int step = 0; step < 3; ++step) {
        gemm_keys<<<RTOT / 32, 256, 0, stream>>>(state, Wn, bn, khi_b, klo_b);
        sim_topk_kernel<<<256, 256, 0, stream>>>(khi_b, klo_b, svals, sidxb);
        gather_mean_kernel<<<RTOT / 4, 256, 0, stream>>>(state, svals, sidxb, Mbuf);
        gemm_d_h<<<RTOT / 32, 256, 0, stream>>>(Mbuf, Wn, bn, keysagg);
        gemm_ln<<<RTOT / 32, 256, 0, stream>>>(state, keysagg, W1, b1, lng, lnb, hbuf);
        gemm_upd<<<RTOT / 32, 256, 0, stream>>>(hbuf, W2, b2, state);
    }
    partial_mean_kernel<<<dim3(32, BQ), 128, 0, stream>>>(state, partial);
    final_out_kernel<<<1, 256, 0, stream>>>(partial, Wo, bo, out);
}

// Round 7
// 3499.920 us; speedup vs baseline: 1.2261x; 1.2261x over previous
//
#include <hip/hip_runtime.h>

#define DDIM 128
#define HDIM 256
#define BQ   4
#define NN   4096
#define RTOT (BQ*NN)

typedef short short8 __attribute__((ext_vector_type(8)));
typedef float f32x16 __attribute__((ext_vector_type(16)));

__device__ inline unsigned short f2bf(float f) {
    unsigned int u = __float_as_uint(f);
    unsigned int r = (u + 0x7fffu + ((u >> 16) & 1u)) >> 16;
    return (unsigned short)r;
}
__device__ inline float bf2f(unsigned short h) {
    return __uint_as_float(((unsigned int)h) << 16);
}

// ---------------- fused sim (K K^T, split-bf16 MFMA, swapped operands) + per-row top-8 ----
// grid 256 (1 block/CU), block 512 = 8 waves (2 waves/SIMD). Block = 64 rows x 4096 cols.
// Wave (rw,cw) = 32 rows x 1024 cols. A (64 rows, K=256, hi+lo = 64 KB) staged ONCE into
// LDS [plane][kseg t][row x16B] via global_load_lds (one barrier total); per-kb A fragments
// read conflict-free by ds_read_b128. B streamed directly L2->regs (round-5 verified layout)
// through a 3-buffer depth-2 static software pipeline. No in-loop barriers.
// Output = sim^T: per-row top-8 lane-local; in-block merge of 8 lists -> final indices.
__global__ __launch_bounds__(512, 2)
void sim_topk_kernel(const unsigned short* __restrict__ khi,
                     const unsigned short* __restrict__ klo,
                     int* __restrict__ idxout) {
    __shared__ __align__(16) char smem[65536];

    const int id = blockIdx.x;
    const int b = (id & 7) >> 1;                    // batch -> XCD pair (L2 residency)
    const int tile = ((id >> 3) << 1) | (id & 1);   // 0..63
    const int rowbase = tile * 64;
    const unsigned short* khiB = khi + (size_t)b * NN * HDIM;
    const unsigned short* kloB = klo + (size_t)b * NN * HDIM;

    const int tid = threadIdx.x;
    const int lane = tid & 63, w = tid >> 6;        // 8 waves
    const int l31 = lane & 31, lh = lane >> 5;
    const int rw = w & 1, cw = w >> 1;              // 2 rowsets x 4 colsets

    // ---- stage A once: unit u=(p,t): dest (p*32+t)*1024 + lane*16 (row=lane), ----
    // ---- src = plane[(rowbase+lane)*HDIM + t*8] (per-lane scatter: allowed)     ----
#pragma unroll
    for (int i = 0; i < 8; ++i) {
        const int u = w * 8 + i;
        const int p = u >> 5, t = u & 31;
        const unsigned short* src = (p ? kloB : khiB) + (size_t)(rowbase + lane) * HDIM + t * 8;
        __builtin_amdgcn_global_load_lds(
            (const __attribute__((address_space(1))) void*)src,
            (__attribute__((address_space(3))) void*)(smem + (p * 32 + t) * 1024), 16, 0, 0);
    }
    asm volatile("s_waitcnt vmcnt(0)" ::: "memory");
    __syncthreads();

    // per-lane A read base: A[(t)*64 + rw*32 + l31]*16, t = 4*kb + 2*tt + lh
    const int aoff = (rw * 32 + l31) * 16 + lh * 1024;

    // B stream base (round-5 verified operand layout): col = cw*1024 + cb*128 + f*32 + l31,
    // k-elems = kb*32 + tt*16 + lh*8
    const unsigned short* pHc = khiB + (size_t)(cw * 1024 + l31) * HDIM + lh * 8;
    const unsigned short* pLc = kloB + (size_t)(cw * 1024 + l31) * HDIM + lh * 8;

    float tv[8]; int ti[8];
#pragma unroll
    for (int s = 0; s < 8; ++s) { tv[s] = -1e30f; ti[s] = 0x7fffffff; }

    auto scan_frag = [&](const f32x16& acc, int cbf) {
#pragma unroll
        for (int r = 0; r < 16; ++r) {
            float v = acc[r];
            int col = cbf + (r & 3) + 8 * (r >> 2);
            if (v > tv[7]) {
                tv[7] = v; ti[7] = col;
#pragma unroll
                for (int q = 7; q >= 1; --q) {
                    if (tv[q] > tv[q - 1]) {
                        float a0 = tv[q]; tv[q] = tv[q - 1]; tv[q - 1] = a0;
                        int   c0 = ti[q]; ti[q] = ti[q - 1]; ti[q - 1] = c0;
                    }
                }
            }
        }
    };

    for (int cb = 0; cb < 8; ++cb) {
        const unsigned short* qH = pHc + (size_t)cb * 128 * HDIM;
        const unsigned short* qL = pLc + (size_t)cb * 128 * HDIM;

        f32x16 acc0, acc1, acc2, acc3;
#pragma unroll
        for (int r = 0; r < 16; ++r) { acc0[r] = 0.f; acc1[r] = 0.f; acc2[r] = 0.f; acc3[r] = 0.f; }

        short8 Ah[3], Al[3], Bh[3][4], Bl[3][4];

        // load pipeline step tau (kb=tau>>1, tt=tau&1) into buffer bi (all indices static)
#define SIM_LD(bi, tau)                                                                             \
        {                                                                                           \
            Ah[bi] = *(const short8*)(smem + aoff + ((tau) >> 1) * 4096 + ((tau) & 1) * 2048);      \
            Al[bi] = *(const short8*)(smem + 32768 + aoff + ((tau) >> 1) * 4096 + ((tau) & 1) * 2048); \
            Bh[bi][0] = *(const short8*)(qH + 0 * 32 * HDIM + ((tau) >> 1) * 32 + ((tau) & 1) * 16);\
            Bh[bi][1] = *(const short8*)(qH + 1 * 32 * HDIM + ((tau) >> 1) * 32 + ((tau) & 1) * 16);\
            Bh[bi][2] = *(const short8*)(qH + 2 * 32 * HDIM + ((tau) >> 1) * 32 + ((tau) & 1) * 16);\
            Bh[bi][3] = *(const short8*)(qH + 3 * 32 * HDIM + ((tau) >> 1) * 32 + ((tau) & 1) * 16);\
            Bl[bi][0] = *(const short8*)(qL + 0 * 32 * HDIM + ((tau) >> 1) * 32 + ((tau) & 1) * 16);\
            Bl[bi][1] = *(const short8*)(qL + 1 * 32 * HDIM + ((tau) >> 1) * 32 + ((tau) & 1) * 16);\
            Bl[bi][2] = *(const short8*)(qL + 2 * 32 * HDIM + ((tau) >> 1) * 32 + ((tau) & 1) * 16);\
            Bl[bi][3] = *(const short8*)(qL + 3 * 32 * HDIM + ((tau) >> 1) * 32 + ((tau) & 1) * 16);\
        }

        SIM_LD(0, 0)
        SIM_LD(1, 1)

#pragma unroll
        for (int tau = 0; tau < 16; ++tau) {
            if (tau + 2 < 16) SIM_LD((tau + 2) % 3, tau + 2)
            const int bi = tau % 3;
            acc0 = __builtin_amdgcn_mfma_f32_32x32x16_bf16(Bh[bi][0], Ah[bi], acc0, 0, 0, 0);
            acc0 = __builtin_amdgcn_mfma_f32_32x32x16_bf16(Bh[bi][0], Al[bi], acc0, 0, 0, 0);
            acc0 = __builtin_amdgcn_mfma_f32_32x32x16_bf16(Bl[bi][0], Ah[bi], acc0, 0, 0, 0);
            acc1 = __builtin_amdgcn_mfma_f32_32x32x16_bf16(Bh[bi][1], Ah[bi], acc1, 0, 0, 0);
            acc1 = __builtin_amdgcn_mfma_f32_32x32x16_bf16(Bh[bi][1], Al[bi], acc1, 0, 0, 0);
            acc1 = __builtin_amdgcn_mfma_f32_32x32x16_bf16(Bl[bi][1], Ah[bi], acc1, 0, 0, 0);
            acc2 = __builtin_amdgcn_mfma_f32_32x32x16_bf16(Bh[bi][2], Ah[bi], acc2, 0, 0, 0);
            acc2 = __builtin_amdgcn_mfma_f32_32x32x16_bf16(Bh[bi][2], Al[bi], acc2, 0, 0, 0);
            acc2 = __builtin_amdgcn_mfma_f32_32x32x16_bf16(Bl[bi][2], Ah[bi], acc2, 0, 0, 0);
            acc3 = __builtin_amdgcn_mfma_f32_32x32x16_bf16(Bh[bi][3], Ah[bi], acc3, 0, 0, 0);
            acc3 = __builtin_amdgcn_mfma_f32_32x32x16_bf16(Bh[bi][3], Al[bi], acc3, 0, 0, 0);
            acc3 = __builtin_amdgcn_mfma_f32_32x32x16_bf16(Bl[bi][3], Ah[bi], acc3, 0, 0, 0);
        }
#undef SIM_LD

        const int cbase = cw * 1024 + cb * 128 + 4 * lh;
        scan_frag(acc0, cbase);
        scan_frag(acc1, cbase + 32);
        scan_frag(acc2, cbase + 64);
        scan_frag(acc3, cbase + 96);
    }

    // ---- merge 8 partial lists per row (4 cw x 2 lh), lexicographic (ties -> lower idx) ----
    __syncthreads();                       // all A reads done; reuse smem
    float* vbuf = (float*)smem;            // [64][66]
    int*   ibuf = (int*)(smem + 64 * 66 * 4);
    const int list = cw * 2 + lh;
    const int mrow = rw * 32 + l31;
#pragma unroll
    for (int s = 0; s < 8; ++s) {
        vbuf[mrow * 66 + list * 8 + s] = tv[s];
        ibuf[mrow * 66 + list * 8 + s] = ti[s];
    }
    __syncthreads();
    if (tid < 64) {
        float fv[8]; int fi[8];
#pragma unroll
        for (int s = 0; s < 8; ++s) { fv[s] = -1e30f; fi[s] = 0x7fffffff; }
        for (int e = 0; e < 64; ++e) {
            float v = vbuf[tid * 66 + e];
            int  ix = ibuf[tid * 66 + e];
            bool ins = (v > fv[7]) || (v == fv[7] && ix < fi[7]);
            if (ins) {
                fv[7] = v; fi[7] = ix;
#pragma unroll
                for (int q = 7; q >= 1; --q) {
                    bool sw = (fv[q] > fv[q - 1]) || (fv[q] == fv[q - 1] && fi[q] < fi[q - 1]);
                    if (sw) {
                        float a0 = fv[q]; fv[q] = fv[q - 1]; fv[q - 1] = a0;
                        int   c0 = fi[q]; fi[q] = fi[q - 1]; fi[q - 1] = c0;
                    }
                }
            }
        }
        size_t basei = ((size_t)b * NN + rowbase + tid) * 8;
#pragma unroll
        for (int s = 0; s < 8; ++s) idxout[basei + s] = fi[s];
    }
}

// ---------------- keys projection GEMM + fused normalize -> khi/klo (bf16 planes) ----------------
__global__ __launch_bounds__(256, 2)
void gemm_keys(const float* __restrict__ A, const float* __restrict__ W,
               const float* __restrict__ bias,
               unsigned short* __restrict__ khi, unsigned short* __restrict__ klo) {
    __shared__ float As[32 * 132];
    int tid = threadIdx.x;
    size_t rowbase = (size_t)blockIdx.x * 32;
    for (int i = tid; i < 32 * 32; i += 256) {
        int r = i >> 5, q = i & 31;
        *(float4*)&As[r * 132 + q * 4] = *(const float4*)&A[(rowbase + r) * DDIM + q * 4];
    }
    __syncthreads();
    int rg = tid >> 5, cg = tid & 31;
    int r0 = rg * 4, c0 = cg * 8;
    float acc[4][8];
#pragma unroll
    for (int i = 0; i < 4; ++i)
#pragma unroll
        for (int j = 0; j < 8; ++j) acc[i][j] = 0.f;

#pragma unroll 2
    for (int k = 0; k < DDIM; k += 4) {
        float a[4][4];
#pragma unroll
        for (int i = 0; i < 4; ++i) {
            float4 t = *(const float4*)&As[(r0 + i) * 132 + k];
            a[i][0] = t.x; a[i][1] = t.y; a[i][2] = t.z; a[i][3] = t.w;
        }
#pragma unroll
        for (int kk = 0; kk < 4; ++kk) {
            float4 w0 = *(const float4*)&W[(size_t)(k + kk) * HDIM + c0];
            float4 w1 = *(const float4*)&W[(size_t)(k + kk) * HDIM + c0 + 4];
            float wv[8] = {w0.x, w0.y, w0.z, w0.w, w1.x, w1.y, w1.z, w1.w};
#pragma unroll
            for (int i = 0; i < 4; ++i)
#pragma unroll
                for (int j = 0; j < 8; ++j) acc[i][j] += a[i][kk] * wv[j];
        }
    }
    float4 bz0 = *(const float4*)&bias[c0];
    float4 bz1 = *(const float4*)&bias[c0 + 4];
    float bz[8] = {bz0.x, bz0.y, bz0.z, bz0.w, bz1.x, bz1.y, bz1.z, bz1.w};
#pragma unroll
    for (int i = 0; i < 4; ++i) {
        float vv[8];
        float ss = 0.f;
#pragma unroll
        for (int j = 0; j < 8; ++j) { vv[j] = acc[i][j] + bz[j]; ss += vv[j]*vv[j]; }
#pragma unroll
        for (int m = 16; m; m >>= 1) ss += __shfl_xor(ss, m);
        float sc = 1.0f / fmaxf(sqrtf(ss), 1e-12f);
        short8 hv, lv;
#pragma unroll
        for (int j = 0; j < 8; ++j) {
            float vn = vv[j] * sc;
            unsigned short h = f2bf(vn);
            hv[j] = (short)h;
            lv[j] = (short)f2bf(vn - bf2f(h));
        }
        *(short8*)&khi[(rowbase + r0 + i) * HDIM + c0] = hv;
        *(short8*)&klo[(rowbase + r0 + i) * HDIM + c0] = lv;
    }
}

// ---------------- agg projection GEMM: out = A(Rx128) @ W(128x256) + bias ----------------
__global__ __launch_bounds__(256, 2)
void gemm_d_h(const float* __restrict__ A, const float* __restrict__ W,
              const float* __restrict__ bias, float* __restrict__ out) {
    __shared__ float As[32 * 132];
    int tid = threadIdx.x;
    size_t rowbase = (size_t)blockIdx.x * 32;
    for (int i = tid; i < 32 * 32; i += 256) {
        int r = i >> 5, q = i & 31;
        *(float4*)&As[r * 132 + q * 4] = *(const float4*)&A[(rowbase + r) * DDIM + q * 4];
    }
    __syncthreads();
    int rg = tid >> 5, cg = tid & 31;
    int r0 = rg * 4, c0 = cg * 8;
    float acc[4][8];
#pragma unroll
    for (int i = 0; i < 4; ++i)
#pragma unroll
        for (int j = 0; j < 8; ++j) acc[i][j] = 0.f;

#pragma unroll 2
    for (int k = 0; k < DDIM; k += 4) {
        float a[4][4];
#pragma unroll
        for (int i = 0; i < 4; ++i) {
            float4 t = *(const float4*)&As[(r0 + i) * 132 + k];
            a[i][0] = t.x; a[i][1] = t.y; a[i][2] = t.z; a[i][3] = t.w;
        }
#pragma unroll
        for (int kk = 0; kk < 4; ++kk) {
            float4 w0 = *(const float4*)&W[(size_t)(k + kk) * HDIM + c0];
            float4 w1 = *(const float4*)&W[(size_t)(k + kk) * HDIM + c0 + 4];
            float wv[8] = {w0.x, w0.y, w0.z, w0.w, w1.x, w1.y, w1.z, w1.w};
#pragma unroll
            for (int i = 0; i < 4; ++i)
#pragma unroll
                for (int j = 0; j < 8; ++j) acc[i][j] += a[i][kk] * wv[j];
        }
    }
    float4 bz0 = *(const float4*)&bias[c0];
    float4 bz1 = *(const float4*)&bias[c0 + 4];
    float bz[8] = {bz0.x, bz0.y, bz0.z, bz0.w, bz1.x, bz1.y, bz1.z, bz1.w};
#pragma unroll
    for (int i = 0; i < 4; ++i) {
        float4 o0, o1;
        o0.x = acc[i][0] + bz[0]; o0.y = acc[i][1] + bz[1]; o0.z = acc[i][2] + bz[2]; o0.w = acc[i][3] + bz[3];
        o1.x = acc[i][4] + bz[4]; o1.y = acc[i][5] + bz[5]; o1.z = acc[i][6] + bz[6]; o1.w = acc[i][7] + bz[7];
        *(float4*)&out[(rowbase + r0 + i) * HDIM + c0] = o0;
        *(float4*)&out[(rowbase + r0 + i) * HDIM + c0 + 4] = o1;
    }
}

// ---------------- gather top-8 rows + mean, 2 rows / block ----------------
__global__ void gather_mean_kernel(const float* __restrict__ state, const int* __restrict__ idx,
                                   float* __restrict__ M) {
    __shared__ int ilds[16];
    int tid = threadIdx.x;
    int row0 = blockIdx.x * 2;
    if (tid < 16) ilds[tid] = idx[(size_t)row0 * 8 + tid];
    __syncthreads();
    int lr = tid >> 7, d = tid & 127;
    int grow = row0 + lr;
    int b = grow >> 12;
    const float* sb = state + (size_t)b * NN * DDIM;
    float acc = 0.f;
#pragma unroll
    for (int k = 0; k < 8; ++k) acc += sb[(size_t)ilds[lr * 8 + k] * DDIM + d];
    M[(size_t)grow * DDIM + d] = acc * 0.125f;
}

// ---------------- concat GEMM (K=384) + LayerNorm epilogue ----------------
__global__ __launch_bounds__(256, 2)
void gemm_ln(const float* __restrict__ state, const float* __restrict__ agg,
             const float* __restrict__ W1, const float* __restrict__ b1,
             const float* __restrict__ lng, const float* __restrict__ lnb,
             float* __restrict__ h) {
    __shared__ float As[32 * 388];
    int tid = threadIdx.x;
    size_t rowbase = (size_t)blockIdx.x * 32;
    for (int i = tid; i < 32 * 96; i += 256) {
        int r = i / 96, q = i % 96;
        float4 v;
        if (q < 32) v = *(const float4*)&state[(rowbase + r) * DDIM + q * 4];
        else        v = *(const float4*)&agg[(rowbase + r) * HDIM + (q - 32) * 4];
        *(float4*)&As[r * 388 + q * 4] = v;
    }
    __syncthreads();
    int rg = tid >> 5, cg = tid & 31;
    int r0 = rg * 4, c0 = cg * 8;
    float acc[4][8];
#pragma unroll
    for (int i = 0; i < 4; ++i)
#pragma unroll
        for (int j = 0; j < 8; ++j) acc[i][j] = 0.f;

#pragma unroll 2
    for (int k = 0; k < 384; k += 4) {
        float a[4][4];
#pragma unroll
        for (int i = 0; i < 4; ++i) {
            float4 t = *(const float4*)&As[(r0 + i) * 388 + k];
            a[i][0] = t.x; a[i][1] = t.y; a[i][2] = t.z; a[i][3] = t.w;
        }
#pragma unroll
        for (int kk = 0; kk < 4; ++kk) {
            float4 w0 = *(const float4*)&W1[(size_t)(k + kk) * HDIM + c0];
            float4 w1 = *(const float4*)&W1[(size_t)(k + kk) * HDIM + c0 + 4];
            float wv[8] = {w0.x, w0.y, w0.z, w0.w, w1.x, w1.y, w1.z, w1.w};
#pragma unroll
            for (int i = 0; i < 4; ++i)
#pragma unroll
                for (int j = 0; j < 8; ++j) acc[i][j] += a[i][kk] * wv[j];
        }
    }
    float4 b10 = *(const float4*)&b1[c0];
    float4 b11 = *(const float4*)&b1[c0 + 4];
    float bb[8] = {b10.x, b10.y, b10.z, b10.w, b11.x, b11.y, b11.z, b11.w};
    float4 g0 = *(const float4*)&lng[c0];
    float4 g1 = *(const float4*)&lng[c0 + 4];
    float lg[8] = {g0.x, g0.y, g0.z, g0.w, g1.x, g1.y, g1.z, g1.w};
    float4 e0 = *(const float4*)&lnb[c0];
    float4 e1 = *(const float4*)&lnb[c0 + 4];
    float lb[8] = {e0.x, e0.y, e0.z, e0.w, e1.x, e1.y, e1.z, e1.w};

#pragma unroll
    for (int i = 0; i < 4; ++i) {
        float s1 = 0.f, s2 = 0.f;
#pragma unroll
        for (int j = 0; j < 8; ++j) {
            acc[i][j] += bb[j];
            s1 += acc[i][j];
            s2 += acc[i][j] * acc[i][j];
        }
#pragma unroll
        for (int m = 16; m; m >>= 1) { s1 += __shfl_xor(s1, m); s2 += __shfl_xor(s2, m); }
        float mu = s1 * (1.0f / HDIM);
        float var = s2 * (1.0f / HDIM) - mu * mu;
        float inv = 1.0f / sqrtf(var + 1e-5f);
        float4 o0, o1;
        o0.x = (acc[i][0] - mu) * inv * lg[0] + lb[0];
        o0.y = (acc[i][1] - mu) * inv * lg[1] + lb[1];
        o0.z = (acc[i][2] - mu) * inv * lg[2] + lb[2];
        o0.w = (acc[i][3] - mu) * inv * lg[3] + lb[3];
        o1.x = (acc[i][4] - mu) * inv * lg[4] + lb[4];
        o1.y = (acc[i][5] - mu) * inv * lg[5] + lb[5];
        o1.z = (acc[i][6] - mu) * inv * lg[6] + lb[6];
        o1.w = (acc[i][7] - mu) * inv * lg[7] + lb[7];
        *(float4*)&h[(rowbase + r0 + i) * HDIM + c0] = o0;
        *(float4*)&h[(rowbase + r0 + i) * HDIM + c0 + 4] = o1;
    }
}

// ---------------- update GEMM: state += silu(h) @ W2 + b2 ----------------
__global__ __launch_bounds__(256, 2)
void gemm_upd(const float* __restrict__ h, const float* __restrict__ W2,
              const float* __restrict__ b2, float* __restrict__ state) {
    __shared__ float As[32 * 260];
    int tid = threadIdx.x;
    size_t rowbase = (size_t)blockIdx.x * 32;
    for (int i = tid; i < 32 * 64; i += 256) {
        int r = i >> 6, q = i & 63;
        float4 v = *(const float4*)&h[(rowbase + r) * HDIM + q * 4];
        v.x = v.x / (1.0f + expf(-v.x));
        v.y = v.y / (1.0f + expf(-v.y));
        v.z = v.z / (1.0f + expf(-v.z));
        v.w = v.w / (1.0f + expf(-v.w));
        *(float4*)&As[r * 260 + q * 4] = v;
    }
    __syncthreads();
    int rg = tid >> 4, cg = tid & 15;
    int r0 = rg * 2, c0 = cg * 8;
    float acc[2][8];
#pragma unroll
    for (int i = 0; i < 2; ++i)
#pragma unroll
        for (int j = 0; j < 8; ++j) acc[i][j] = 0.f;

#pragma unroll 2
    for (int k = 0; k < HDIM; k += 4) {
        float a[2][4];
#pragma unroll
        for (int i = 0; i < 2; ++i) {
            float4 t = *(const float4*)&As[(r0 + i) * 260 + k];
            a[i][0] = t.x; a[i][1] = t.y; a[i][2] = t.z; a[i][3] = t.w;
        }
#pragma unroll
        for (int kk = 0; kk < 4; ++kk) {
            float4 w0 = *(const float4*)&W2[(size_t)(k + kk) * DDIM + c0];
            float4 w1 = *(const float4*)&W2[(size_t)(k + kk) * DDIM + c0 + 4];
            float wv[8] = {w0.x, w0.y, w0.z, w0.w, w1.x, w1.y, w1.z, w1.w};
#pragma unroll
            for (int i = 0; i < 2; ++i)
#pragma unroll
                for (int j = 0; j < 8; ++j) acc[i][j] += a[i][kk] * wv[j];
        }
    }
    float4 bz0 = *(const float4*)&b2[c0];
    float4 bz1 = *(const float4*)&b2[c0 + 4];
    float bz[8] = {bz0.x, bz0.y, bz0.z, bz0.w, bz1.x, bz1.y, bz1.z, bz1.w};
#pragma unroll
    for (int i = 0; i < 2; ++i) {
        size_t off = (rowbase + r0 + i) * DDIM + c0;
        float4 s0 = *(const float4*)&state[off];
        float4 s1 = *(const float4*)&state[off + 4];
        s0.x += acc[i][0] + bz[0]; s0.y += acc[i][1] + bz[1];
        s0.z += acc[i][2] + bz[2]; s0.w += acc[i][3] + bz[3];
        s1.x += acc[i][4] + bz[4]; s1.y += acc[i][5] + bz[5];
        s1.z += acc[i][6] + bz[6]; s1.w += acc[i][7] + bz[7];
        *(float4*)&state[off] = s0;
        *(float4*)&state[off + 4] = s1;
    }
}

// ---------------- final: mean over N, then @ Wo + bo ----------------
__global__ void partial_mean_kernel(const float* __restrict__ state, float* __restrict__ partial) {
    int b = blockIdx.y, seg = blockIdx.x, tid = threadIdx.x;  // 128 threads
    const float* sp = state + ((size_t)b * NN + (size_t)seg * 128) * DDIM;
    float acc = 0.f;
    for (int i = 0; i < 128; ++i) acc += sp[(size_t)i * DDIM + tid];
    partial[((size_t)b * 32 + seg) * DDIM + tid] = acc;
}

__global__ void final_out_kernel(const float* __restrict__ partial, const float* __restrict__ Wo,
                                 const float* __restrict__ bo, float* __restrict__ out) {
    __shared__ float mean[BQ][DDIM];
    int tid = threadIdx.x;
    for (int o = tid; o < BQ * DDIM; o += 256) {
        int b = o >> 7, d = o & 127;
        float s = 0.f;
        for (int p = 0; p < 32; ++p) s += partial[((size_t)b * 32 + p) * DDIM + d];
        mean[b][d] = s * (1.0f / NN);
    }
    __syncthreads();
    for (int o = tid; o < BQ * DDIM; o += 256) {
        int b = o >> 7, c = o & 127;
        float acc = bo[c];
        for (int d = 0; d < DDIM; ++d) acc += mean[b][d] * Wo[d * DDIM + c];
        out[o] = acc;
    }
}

extern "C" void kernel_launch(void* const* d_in, const int* in_sizes, int n_in,
                              void* d_out, int out_size, void* d_ws, size_t ws_size,
                              hipStream_t stream) {
    const float* x   = (const float*)d_in[0];
    const float* Wn  = (const float*)d_in[1];
    const float* bn  = (const float*)d_in[2];
    const float* W1  = (const float*)d_in[3];
    const float* b1  = (const float*)d_in[4];
    const float* lng = (const float*)d_in[5];
    const float* lnb = (const float*)d_in[6];
    const float* W2  = (const float*)d_in[7];
    const float* b2  = (const float*)d_in[8];
    const float* Wo  = (const float*)d_in[9];
    const float* bo  = (const float*)d_in[10];
    float* out = (float*)d_out;

    float* ws      = (float*)d_ws;
    float* state   = ws;                                        // R*128 f32
    float* keysagg = state + (size_t)RTOT * DDIM;               // R*256 f32
    float* hbuf    = keysagg + (size_t)RTOT * HDIM;             // R*256 f32
    unsigned short* khi_b = (unsigned short*)hbuf;              // R*256 bf16
    unsigned short* klo_b = khi_b + (size_t)RTOT * HDIM;        // R*256 bf16
    float* Mbuf    = hbuf;                                      // R*128 f32 (after sim)
    float* partial = hbuf + (size_t)RTOT * HDIM;                // B*32*128
    int*   idxbuf  = (int*)(partial + (size_t)BQ * 32 * DDIM);  // R*8 ints

    hipMemcpyAsync(state, x, (size_t)RTOT * DDIM * sizeof(float),
                   hipMemcpyDeviceToDevice, stream);

    for (int step = 0; step < 3; ++step) {
        gemm_keys<<<RTOT / 32, 256, 0, stream>>>(state, Wn, bn, khi_b, klo_b);
        sim_topk_kernel<<<256, 512, 0, stream>>>(khi_b, klo_b, idxbuf);
        gather_mean_kernel<<<RTOT / 2, 256, 0, stream>>>(state, idxbuf, Mbuf);
        gemm_d_h<<<RTOT / 32, 256, 0, stream>>>(Mbuf, Wn, bn, keysagg);
        gemm_ln<<<RTOT / 32, 256, 0, stream>>>(state, keysagg, W1, b1, lng, lnb, hbuf);
        gemm_upd<<<RTOT / 32, 256, 0, stream>>>(hbuf, W2, b2, state);
    }
    partial_mean_kernel<<<dim3(32, BQ), 128, 0, stream>>>(state, partial);
    final_out_kernel<<<1, 256, 0, stream>>>(partial, Wo, bo, out);
}

// Round 8
// 1084.822 us; speedup vs baseline: 3.9557x; 3.2263x over previous
//
#include <hip/hip_runtime.h>

#define DDIM 128
#define HDIM 256
#define BQ   4
#define NN   4096
#define RTOT (BQ*NN)

typedef short short8 __attribute__((ext_vector_type(8)));
typedef float f32x16 __attribute__((ext_vector_type(16)));

__device__ inline unsigned short f2bf(float f) {
    unsigned int u = __float_as_uint(f);
    unsigned int r = (u + 0x7fffu + ((u >> 16) & 1u)) >> 16;
    return (unsigned short)r;
}
__device__ inline float bf2f(unsigned short h) {
    return __uint_as_float(((unsigned int)h) << 16);
}

// ---------------- fused sim (K K^T, split-bf16 MFMA, swapped operands) + per-row top-8 ----
// grid 512 (2 blocks/CU), block 256 = 4 waves (2 waves/SIMD). Block = 32 rows x 4096 cols;
// wave = 32 rows x 1024 cols. A (32 rows, hi+lo, full K) in regs (round-5 proven, VGPR 108).
// B now staged through WAVE-PRIVATE LDS chunks (32 cols x K32 x hi/lo = 4 KB, 3 buffers)
// with COALESCED global_load_lds (lane = contiguous 16B within a 1KB span -> 16 lines/KB,
// vs 64 lines/instr for the direct layout) and seg-XOR source pre-swizzle (involution) so
// ds_read_b128 operand reads are low-conflict. Prefetch distance 2, counted vmcnt, zero
// barriers in the loop. Output = sim^T: per-row top-8 lane-local; in-block 8-list merge.
__global__ __launch_bounds__(256, 2)
void sim_topk_kernel(const unsigned short* __restrict__ khi,
                     const unsigned short* __restrict__ klo,
                     int* __restrict__ idxout) {
    __shared__ __align__(16) char smem[4 * 3 * 4096];   // 4 waves x 3 bufs x 4KB = 48 KB

    const int id = blockIdx.x;
    const int xcd = id & 7;
    const int b = xcd >> 1;                       // batch -> XCD pair (L2 residency)
    const int j = ((id >> 3) << 1) | (xcd & 1);   // tile 0..127
    const int rowbase = j * 32;
    const unsigned short* khiB = khi + (size_t)b * NN * HDIM;
    const unsigned short* kloB = klo + (size_t)b * NN * HDIM;

    const int tid = threadIdx.x;
    const int lane = tid & 63, w = tid >> 6;
    const int l31 = lane & 31, lh = lane >> 5;

    // ---- A: 32 rows (hi+lo), full K=256, in regs (MFMA B-operand; round-5 layout) ----
    short8 ah[16], al[16];
    {
        const unsigned short* ph = khiB + (size_t)(rowbase + l31) * HDIM + lh * 8;
        const unsigned short* pl = kloB + (size_t)(rowbase + l31) * HDIM + lh * 8;
#pragma unroll
        for (int T = 0; T < 16; ++T) {
            ah[T] = *(const short8*)(ph + T * 16);
            al[T] = *(const short8*)(pl + T * 16);
        }
    }
#pragma unroll
    for (int T = 0; T < 16; ++T) {
        asm volatile("" : "+v"(ah[T]));
        asm volatile("" : "+v"(al[T]));
    }

    char* mybuf = smem + w * 12288;               // wave-private 3 x 4KB

    // ---- staging: chunk s = (cs, ks): cols [w*1024+cs*32, +32), K [ks*32, +32), hi+lo ----
    // 4 instrs x 1KB, each: lane=(c,sg) c=lane>>2 (16 cols), sg=lane&3 (4 segs of 16B).
    // Source seg pre-swizzled sg^(c&3) (involution); LDS dest linear [plane][col][seg].
    // Coalesced: each instr spans 16 cols x 64B contiguous pieces = 16 lines.
    const int sc = lane >> 2, sg = lane & 3;
    const int ssw = (sg ^ (sc & 3)) * 8;          // element offset of swizzled 16B seg
    auto stage = [&](int s) {
        const int cs2 = s >> 3, ks2 = s & 7;
        char* dst = mybuf + (s % 3) * 4096;
        const int c0 = w * 1024 + cs2 * 32;
#pragma unroll
        for (int p = 0; p < 2; ++p) {
            const unsigned short* pb = p ? kloB : khiB;
#pragma unroll
            for (int i = 0; i < 2; ++i) {
                const unsigned short* src = pb + (size_t)(c0 + i * 16 + sc) * HDIM + ks2 * 32 + ssw;
                __builtin_amdgcn_global_load_lds(
                    (const __attribute__((address_space(1))) void*)src,
                    (__attribute__((address_space(3))) void*)(dst + p * 2048 + i * 1024), 16, 0, 0);
            }
        }
    };

    stage(0);
    stage(1);

    float tv[8]; int ti[8];
#pragma unroll
    for (int s = 0; s < 8; ++s) { tv[s] = -1e30f; ti[s] = 0x7fffffff; }

    for (int cs = 0; cs < 32; ++cs) {
        f32x16 acc;
#pragma unroll
        for (int r = 0; r < 16; ++r) acc[r] = 0.f;

#pragma unroll
        for (int ks = 0; ks < 8; ++ks) {
            const int s = cs * 8 + ks;
            // prior chunk's ds_reads done before its buffer is overwritten by stage(s+2)
            asm volatile("s_waitcnt lgkmcnt(0)" ::: "memory");
            if (s + 2 < 256) stage(s + 2);
            if (s < 254)       asm volatile("s_waitcnt vmcnt(8)" ::: "memory");
            else if (s == 254) asm volatile("s_waitcnt vmcnt(4)" ::: "memory");
            else               asm volatile("s_waitcnt vmcnt(0)" ::: "memory");

            const char* bufc = mybuf + (s % 3) * 4096;
#pragma unroll
            for (int kk = 0; kk < 2; ++kk) {
                const int T = ks * 2 + kk;
                const int rb = l31 * 64 + (((kk * 2 + lh) ^ (l31 & 3)) * 16);
                short8 Bh = *(const short8*)(bufc + rb);
                short8 Bl = *(const short8*)(bufc + 2048 + rb);
                acc = __builtin_amdgcn_mfma_f32_32x32x16_bf16(Bh, ah[T], acc, 0, 0, 0);
                acc = __builtin_amdgcn_mfma_f32_32x32x16_bf16(Bh, al[T], acc, 0, 0, 0);
                acc = __builtin_amdgcn_mfma_f32_32x32x16_bf16(Bl, ah[T], acc, 0, 0, 0);
            }
        }

        // scan 16 lane-local sim values (ascending col; strict > = ref tie semantics)
        const int cbase = w * 1024 + cs * 32 + 4 * lh;
#pragma unroll
        for (int r = 0; r < 16; ++r) {
            float v = acc[r];
            int col = cbase + (r & 3) + 8 * (r >> 2);
            if (v > tv[7]) {
                tv[7] = v; ti[7] = col;
#pragma unroll
                for (int q = 7; q >= 1; --q) {
                    if (tv[q] > tv[q - 1]) {
                        float a0 = tv[q]; tv[q] = tv[q - 1]; tv[q - 1] = a0;
                        int   c0_ = ti[q]; ti[q] = ti[q - 1]; ti[q - 1] = c0_;
                    }
                }
            }
        }
    }

    // ---- merge 8 partial lists per row (4 waves x 2 lh), lexicographic ----
    __syncthreads();
    float* vbuf = (float*)smem;               // [32][66]
    int*   ibuf = (int*)(smem + 32 * 66 * 4);
    const int list = w * 2 + lh;
#pragma unroll
    for (int s = 0; s < 8; ++s) {
        vbuf[l31 * 66 + list * 8 + s] = tv[s];
        ibuf[l31 * 66 + list * 8 + s] = ti[s];
    }
    __syncthreads();
    if (tid < 32) {
        float fv[8]; int fi[8];
#pragma unroll
        for (int s = 0; s < 8; ++s) { fv[s] = -1e30f; fi[s] = 0x7fffffff; }
        for (int e = 0; e < 64; ++e) {
            float v = vbuf[tid * 66 + e];
            int  ix = ibuf[tid * 66 + e];
            bool ins = (v > fv[7]) || (v == fv[7] && ix < fi[7]);
            if (ins) {
                fv[7] = v; fi[7] = ix;
#pragma unroll
                for (int q = 7; q >= 1; --q) {
                    bool sw = (fv[q] > fv[q - 1]) || (fv[q] == fv[q - 1] && fi[q] < fi[q - 1]);
                    if (sw) {
                        float a0 = fv[q]; fv[q] = fv[q - 1]; fv[q - 1] = a0;
                        int   c0_ = fi[q]; fi[q] = fi[q - 1]; fi[q - 1] = c0_;
                    }
                }
            }
        }
        size_t basei = ((size_t)b * NN + rowbase + tid) * 8;
#pragma unroll
        for (int s = 0; s < 8; ++s) idxout[basei + s] = fi[s];
    }
}

// ---------------- keys projection GEMM + fused normalize -> khi/klo (bf16 planes) ----------------
__global__ __launch_bounds__(256, 2)
void gemm_keys(const float* __restrict__ A, const float* __restrict__ W,
               const float* __restrict__ bias,
               unsigned short* __restrict__ khi, unsigned short* __restrict__ klo) {
    __shared__ float As[32 * 132];
    int tid = threadIdx.x;
    size_t rowbase = (size_t)blockIdx.x * 32;
    for (int i = tid; i < 32 * 32; i += 256) {
        int r = i >> 5, q = i & 31;
        *(float4*)&As[r * 132 + q * 4] = *(const float4*)&A[(rowbase + r) * DDIM + q * 4];
    }
    __syncthreads();
    int rg = tid >> 5, cg = tid & 31;
    int r0 = rg * 4, c0 = cg * 8;
    float acc[4][8];
#pragma unroll
    for (int i = 0; i < 4; ++i)
#pragma unroll
        for (int j = 0; j < 8; ++j) acc[i][j] = 0.f;

#pragma unroll 2
    for (int k = 0; k < DDIM; k += 4) {
        float a[4][4];
#pragma unroll
        for (int i = 0; i < 4; ++i) {
            float4 t = *(const float4*)&As[(r0 + i) * 132 + k];
            a[i][0] = t.x; a[i][1] = t.y; a[i][2] = t.z; a[i][3] = t.w;
        }
#pragma unroll
        for (int kk = 0; kk < 4; ++kk) {
            float4 w0 = *(const float4*)&W[(size_t)(k + kk) * HDIM + c0];
            float4 w1 = *(const float4*)&W[(size_t)(k + kk) * HDIM + c0 + 4];
            float wv[8] = {w0.x, w0.y, w0.z, w0.w, w1.x, w1.y, w1.z, w1.w};
#pragma unroll
            for (int i = 0; i < 4; ++i)
#pragma unroll
                for (int j = 0; j < 8; ++j) acc[i][j] += a[i][kk] * wv[j];
        }
    }
    float4 bz0 = *(const float4*)&bias[c0];
    float4 bz1 = *(const float4*)&bias[c0 + 4];
    float bz[8] = {bz0.x, bz0.y, bz0.z, bz0.w, bz1.x, bz1.y, bz1.z, bz1.w};
#pragma unroll
    for (int i = 0; i < 4; ++i) {
        float vv[8];
        float ss = 0.f;
#pragma unroll
        for (int j = 0; j < 8; ++j) { vv[j] = acc[i][j] + bz[j]; ss += vv[j]*vv[j]; }
#pragma unroll
        for (int m = 16; m; m >>= 1) ss += __shfl_xor(ss, m);
        float sc = 1.0f / fmaxf(sqrtf(ss), 1e-12f);
        short8 hv, lv;
#pragma unroll
        for (int j = 0; j < 8; ++j) {
            float vn = vv[j] * sc;
            unsigned short h = f2bf(vn);
            hv[j] = (short)h;
            lv[j] = (short)f2bf(vn - bf2f(h));
        }
        *(short8*)&khi[(rowbase + r0 + i) * HDIM + c0] = hv;
        *(short8*)&klo[(rowbase + r0 + i) * HDIM + c0] = lv;
    }
}

// ---------------- agg projection GEMM: out = A(Rx128) @ W(128x256) + bias ----------------
__global__ __launch_bounds__(256, 2)
void gemm_d_h(const float* __restrict__ A, const float* __restrict__ W,
              const float* __restrict__ bias, float* __restrict__ out) {
    __shared__ float As[32 * 132];
    int tid = threadIdx.x;
    size_t rowbase = (size_t)blockIdx.x * 32;
    for (int i = tid; i < 32 * 32; i += 256) {
        int r = i >> 5, q = i & 31;
        *(float4*)&As[r * 132 + q * 4] = *(const float4*)&A[(rowbase + r) * DDIM + q * 4];
    }
    __syncthreads();
    int rg = tid >> 5, cg = tid & 31;
    int r0 = rg * 4, c0 = cg * 8;
    float acc[4][8];
#pragma unroll
    for (int i = 0; i < 4; ++i)
#pragma unroll
        for (int j = 0; j < 8; ++j) acc[i][j] = 0.f;

#pragma unroll 2
    for (int k = 0; k < DDIM; k += 4) {
        float a[4][4];
#pragma unroll
        for (int i = 0; i < 4; ++i) {
            float4 t = *(const float4*)&As[(r0 + i) * 132 + k];
            a[i][0] = t.x; a[i][1] = t.y; a[i][2] = t.z; a[i][3] = t.w;
        }
#pragma unroll
        for (int kk = 0; kk < 4; ++kk) {
            float4 w0 = *(const float4*)&W[(size_t)(k + kk) * HDIM + c0];
            float4 w1 = *(const float4*)&W[(size_t)(k + kk) * HDIM + c0 + 4];
            float wv[8] = {w0.x, w0.y, w0.z, w0.w, w1.x, w1.y, w1.z, w1.w};
#pragma unroll
            for (int i = 0; i < 4; ++i)
#pragma unroll
                for (int j = 0; j < 8; ++j) acc[i][j] += a[i][kk] * wv[j];
        }
    }
    float4 bz0 = *(const float4*)&bias[c0];
    float4 bz1 = *(const float4*)&bias[c0 + 4];
    float bz[8] = {bz0.x, bz0.y, bz0.z, bz0.w, bz1.x, bz1.y, bz1.z, bz1.w};
#pragma unroll
    for (int i = 0; i < 4; ++i) {
        float4 o0, o1;
        o0.x = acc[i][0] + bz[0]; o0.y = acc[i][1] + bz[1]; o0.z = acc[i][2] + bz[2]; o0.w = acc[i][3] + bz[3];
        o1.x = acc[i][4] + bz[4]; o1.y = acc[i][5] + bz[5]; o1.z = acc[i][6] + bz[6]; o1.w = acc[i][7] + bz[7];
        *(float4*)&out[(rowbase + r0 + i) * HDIM + c0] = o0;
        *(float4*)&out[(rowbase + r0 + i) * HDIM + c0 + 4] = o1;
    }
}

// ---------------- gather top-8 rows + mean, 2 rows / block ----------------
__global__ void gather_mean_kernel(const float* __restrict__ state, const int* __restrict__ idx,
                                   float* __restrict__ M) {
    __shared__ int ilds[16];
    int tid = threadIdx.x;
    int row0 = blockIdx.x * 2;
    if (tid < 16) ilds[tid] = idx[(size_t)row0 * 8 + tid];
    __syncthreads();
    int lr = tid >> 7, d = tid & 127;
    int grow = row0 + lr;
    int b = grow >> 12;
    const float* sb = state + (size_t)b * NN * DDIM;
    float acc = 0.f;
#pragma unroll
    for (int k = 0; k < 8; ++k) acc += sb[(size_t)ilds[lr * 8 + k] * DDIM + d];
    M[(size_t)grow * DDIM + d] = acc * 0.125f;
}

// ---------------- concat GEMM (K=384) + LayerNorm epilogue ----------------
__global__ __launch_bounds__(256, 2)
void gemm_ln(const float* __restrict__ state, const float* __restrict__ agg,
             const float* __restrict__ W1, const float* __restrict__ b1,
             const float* __restrict__ lng, const float* __restrict__ lnb,
             float* __restrict__ h) {
    __shared__ float As[32 * 388];
    int tid = threadIdx.x;
    size_t rowbase = (size_t)blockIdx.x * 32;
    for (int i = tid; i < 32 * 96; i += 256) {
        int r = i / 96, q = i % 96;
        float4 v;
        if (q < 32) v = *(const float4*)&state[(rowbase + r) * DDIM + q * 4];
        else        v = *(const float4*)&agg[(rowbase + r) * HDIM + (q - 32) * 4];
        *(float4*)&As[r * 388 + q * 4] = v;
    }
    __syncthreads();
    int rg = tid >> 5, cg = tid & 31;
    int r0 = rg * 4, c0 = cg * 8;
    float acc[4][8];
#pragma unroll
    for (int i = 0; i < 4; ++i)
#pragma unroll
        for (int j = 0; j < 8; ++j) acc[i][j] = 0.f;

#pragma unroll 2
    for (int k = 0; k < 384; k += 4) {
        float a[4][4];
#pragma unroll
        for (int i = 0; i < 4; ++i) {
            float4 t = *(const float4*)&As[(r0 + i) * 388 + k];
            a[i][0] = t.x; a[i][1] = t.y; a[i][2] = t.z; a[i][3] = t.w;
        }
#pragma unroll
        for (int kk = 0; kk < 4; ++kk) {
            float4 w0 = *(const float4*)&W1[(size_t)(k + kk) * HDIM + c0];
            float4 w1 = *(const float4*)&W1[(size_t)(k + kk) * HDIM + c0 + 4];
            float wv[8] = {w0.x, w0.y, w0.z, w0.w, w1.x, w1.y, w1.z, w1.w};
#pragma unroll
            for (int i = 0; i < 4; ++i)
#pragma unroll
                for (int j = 0; j < 8; ++j) acc[i][j] += a[i][kk] * wv[j];
        }
    }
    float4 b10 = *(const float4*)&b1[c0];
    float4 b11 = *(const float4*)&b1[c0 + 4];
    float bb[8] = {b10.x, b10.y, b10.z, b10.w, b11.x, b11.y, b11.z, b11.w};
    float4 g0 = *(const float4*)&lng[c0];
    float4 g1 = *(const float4*)&lng[c0 + 4];
    float lg[8] = {g0.x, g0.y, g0.z, g0.w, g1.x, g1.y, g1.z, g1.w};
    float4 e0 = *(const float4*)&lnb[c0];
    float4 e1 = *(const float4*)&lnb[c0 + 4];
    float lb[8] = {e0.x, e0.y, e0.z, e0.w, e1.x, e1.y, e1.z, e1.w};

#pragma unroll
    for (int i = 0; i < 4; ++i) {
        float s1 = 0.f, s2 = 0.f;
#pragma unroll
        for (int j = 0; j < 8; ++j) {
            acc[i][j] += bb[j];
            s1 += acc[i][j];
            s2 += acc[i][j] * acc[i][j];
        }
#pragma unroll
        for (int m = 16; m; m >>= 1) { s1 += __shfl_xor(s1, m); s2 += __shfl_xor(s2, m); }
        float mu = s1 * (1.0f / HDIM);
        float var = s2 * (1.0f / HDIM) - mu * mu;
        float inv = 1.0f / sqrtf(var + 1e-5f);
        float4 o0, o1;
        o0.x = (acc[i][0] - mu) * inv * lg[0] + lb[0];
        o0.y = (acc[i][1] - mu) * inv * lg[1] + lb[1];
        o0.z = (acc[i][2] - mu) * inv * lg[2] + lb[2];
        o0.w = (acc[i][3] - mu) * inv * lg[3] + lb[3];
        o1.x = (acc[i][4] - mu) * inv * lg[4] + lb[4];
        o1.y = (acc[i][5] - mu) * inv * lg[5] + lb[5];
        o1.z = (acc[i][6] - mu) * inv * lg[6] + lb[6];
        o1.w = (acc[i][7] - mu) * inv * lg[7] + lb[7];
        *(float4*)&h[(rowbase + r0 + i) * HDIM + c0] = o0;
        *(float4*)&h[(rowbase + r0 + i) * HDIM + c0 + 4] = o1;
    }
}

// ---------------- update GEMM: state += silu(h) @ W2 + b2 ----------------
__global__ __launch_bounds__(256, 2)
void gemm_upd(const float* __restrict__ h, const float* __restrict__ W2,
              const float* __restrict__ b2, float* __restrict__ state) {
    __shared__ float As[32 * 260];
    int tid = threadIdx.x;
    size_t rowbase = (size_t)blockIdx.x * 32;
    for (int i = tid; i < 32 * 64; i += 256) {
        int r = i >> 6, q = i & 63;
        float4 v = *(const float4*)&h[(rowbase + r) * HDIM + q * 4];
        v.x = v.x / (1.0f + expf(-v.x));
        v.y = v.y / (1.0f + expf(-v.y));
        v.z = v.z / (1.0f + expf(-v.z));
        v.w = v.w / (1.0f + expf(-v.w));
        *(float4*)&As[r * 260 + q * 4] = v;
    }
    __syncthreads();
    int rg = tid >> 4, cg = tid & 15;
    int r0 = rg * 2, c0 = cg * 8;
    float acc[2][8];
#pragma unroll
    for (int i = 0; i < 2; ++i)
#pragma unroll
        for (int j = 0; j < 8; ++j) acc[i][j] = 0.f;

#pragma unroll 2
    for (int k = 0; k < HDIM; k += 4) {
        float a[2][4];
#pragma unroll
        for (int i = 0; i < 2; ++i) {
            float4 t = *(const float4*)&As[(r0 + i) * 260 + k];
            a[i][0] = t.x; a[i][1] = t.y; a[i][2] = t.z; a[i][3] = t.w;
        }
#pragma unroll
        for (int kk = 0; kk < 4; ++kk) {
            float4 w0 = *(const float4*)&W2[(size_t)(k + kk) * DDIM + c0];
            float4 w1 = *(const float4*)&W2[(size_t)(k + kk) * DDIM + c0 + 4];
            float wv[8] = {w0.x, w0.y, w0.z, w0.w, w1.x, w1.y, w1.z, w1.w};
#pragma unroll
            for (int i = 0; i < 2; ++i)
#pragma unroll
                for (int j = 0; j < 8; ++j) acc[i][j] += a[i][kk] * wv[j];
        }
    }
    float4 bz0 = *(const float4*)&b2[c0];
    float4 bz1 = *(const float4*)&b2[c0 + 4];
    float bz[8] = {bz0.x, bz0.y, bz0.z, bz0.w, bz1.x, bz1.y, bz1.z, bz1.w};
#pragma unroll
    for (int i = 0; i < 2; ++i) {
        size_t off = (rowbase + r0 + i) * DDIM + c0;
        float4 s0 = *(const float4*)&state[off];
        float4 s1 = *(const float4*)&state[off + 4];
        s0.x += acc[i][0] + bz[0]; s0.y += acc[i][1] + bz[1];
        s0.z += acc[i][2] + bz[2]; s0.w += acc[i][3] + bz[3];
        s1.x += acc[i][4] + bz[4]; s1.y += acc[i][5] + bz[5];
        s1.z += acc[i][6] + bz[6]; s1.w += acc[i][7] + bz[7];
        *(float4*)&state[off] = s0;
        *(float4*)&state[off + 4] = s1;
    }
}

// ---------------- final: mean over N, then @ Wo + bo ----------------
__global__ void partial_mean_kernel(const float* __restrict__ state, float* __restrict__ partial) {
    int b = blockIdx.y, seg = blockIdx.x, tid = threadIdx.x;  // 128 threads
    const float* sp = state + ((size_t)b * NN + (size_t)seg * 128) * DDIM;
    float acc = 0.f;
    for (int i = 0; i < 128; ++i) acc += sp[(size_t)i * DDIM + tid];
    partial[((size_t)b * 32 + seg) * DDIM + tid] = acc;
}

__global__ void final_out_kernel(const float* __restrict__ partial, const float* __restrict__ Wo,
                                 const float* __restrict__ bo, float* __restrict__ out) {
    __shared__ float mean[BQ][DDIM];
    int tid = threadIdx.x;
    for (int o = tid; o < BQ * DDIM; o += 256) {
        int b = o >> 7, d = o & 127;
        float s = 0.f;
        for (int p = 0; p < 32; ++p) s += partial[((size_t)b * 32 + p) * DDIM + d];
        mean[b][d] = s * (1.0f / NN);
    }
    __syncthreads();
    for (int o = tid; o < BQ * DDIM; o += 256) {
        int b = o >> 7, c = o & 127;
        float acc = bo[c];
        for (int d = 0; d < DDIM; ++d) acc += mean[b][d] * Wo[d * DDIM + c];
        out[o] = acc;
    }
}

extern "C" void kernel_launch(void* const* d_in, const int* in_sizes, int n_in,
                              void* d_out, int out_size, void* d_ws, size_t ws_size,
                              hipStream_t stream) {
    const float* x   = (const float*)d_in[0];
    const float* Wn  = (const float*)d_in[1];
    const float* bn  = (const float*)d_in[2];
    const float* W1  = (const float*)d_in[3];
    const float* b1  = (const float*)d_in[4];
    const float* lng = (const float*)d_in[5];
    const float* lnb = (const float*)d_in[6];
    const float* W2  = (const float*)d_in[7];
    const float* b2  = (const float*)d_in[8];
    const float* Wo  = (const float*)d_in[9];
    const float* bo  = (const float*)d_in[10];
    float* out = (float*)d_out;

    float* ws      = (float*)d_ws;
    float* state   = ws;                                        // R*128 f32
    float* keysagg = state + (size_t)RTOT * DDIM;               // R*256 f32
    float* hbuf    = keysagg + (size_t)RTOT * HDIM;             // R*256 f32
    unsigned short* khi_b = (unsigned short*)hbuf;              // R*256 bf16
    unsigned short* klo_b = khi_b + (size_t)RTOT * HDIM;        // R*256 bf16
    float* Mbuf    = hbuf;                                      // R*128 f32 (after sim)
    float* partial = hbuf + (size_t)RTOT * HDIM;                // B*32*128
    int*   idxbuf  = (int*)(partial + (size_t)BQ * 32 * DDIM);  // R*8 ints

    hipMemcpyAsync(state, x, (size_t)RTOT * DDIM * sizeof(float),
                   hipMemcpyDeviceToDevice, stream);

    for (int step = 0; step < 3; ++step) {
        gemm_keys<<<RTOT / 32, 256, 0, stream>>>(state, Wn, bn, khi_b, klo_b);
        sim_topk_kernel<<<512, 256, 0, stream>>>(khi_b, klo_b, idxbuf);
        gather_mean_kernel<<<RTOT / 2, 256, 0, stream>>>(state, idxbuf, Mbuf);
        gemm_d_h<<<RTOT / 32, 256, 0, stream>>>(Mbuf, Wn, bn, keysagg);
        gemm_ln<<<RTOT / 32, 256, 0, stream>>>(state, keysagg, W1, b1, lng, lnb, hbuf);
        gemm_upd<<<RTOT / 32, 256, 0, stream>>>(hbuf, W2, b2, state);
    }
    partial_mean_kernel<<<dim3(32, BQ), 128, 0, stream>>>(state, partial);
    final_out_kernel<<<1, 256, 0, stream>>>(partial, Wo, bo, out);
}

// Round 9
// 1051.411 us; speedup vs baseline: 4.0814x; 1.0318x over previous
//
#include <hip/hip_runtime.h>

#define DDIM 128
#define HDIM 256
#define BQ   4
#define NN   4096
#define RTOT (BQ*NN)

typedef short short8 __attribute__((ext_vector_type(8)));
typedef float f32x16 __attribute__((ext_vector_type(16)));

__device__ inline unsigned short f2bf(float f) {
    unsigned int u = __float_as_uint(f);
    unsigned int r = (u + 0x7fffu + ((u >> 16) & 1u)) >> 16;
    return (unsigned short)r;
}
__device__ inline float bf2f(unsigned short h) {
    return __uint_as_float(((unsigned int)h) << 16);
}

// ---------------- fused sim (K K^T, split-bf16 MFMA, swapped operands) + per-row top-8 ----
// grid 512 (2 blocks/CU), block 256 = 4 waves (2 waves/SIMD). Block = 32 rows x 4096 cols;
// wave = 32 rows x 1024 cols. A (32 rows, hi+lo, full K) in regs (VGPR ~112, no spills).
// B staged via coalesced global_load_lds into wave-private 4KB chunks (3 buffers).
// Round-9 changes vs round 8:
//  (1) conflict-free swizzle key (l31>>1)&3: each 8-lane ds_read_b128 group now covers
//      all 32 banks bijectively (was 2-way+ conflicted with l31&3 -> 2.5e7 conflicts).
//  (2) ds_reads issued BEFORE counted lgkmcnt(4) + stage: only the PREVIOUS step's reads
//      are drained (buffer-overwrite hazard), this step's stay in flight under the MFMAs.
__global__ __launch_bounds__(256, 2)
void sim_topk_kernel(const unsigned short* __restrict__ khi,
                     const unsigned short* __restrict__ klo,
                     int* __restrict__ idxout) {
    __shared__ __align__(16) char smem[4 * 3 * 4096];   // 4 waves x 3 bufs x 4KB = 48 KB

    const int id = blockIdx.x;
    const int xcd = id & 7;
    const int b = xcd >> 1;                       // batch -> XCD pair (L2 residency)
    const int j = ((id >> 3) << 1) | (xcd & 1);   // tile 0..127
    const int rowbase = j * 32;
    const unsigned short* khiB = khi + (size_t)b * NN * HDIM;
    const unsigned short* kloB = klo + (size_t)b * NN * HDIM;

    const int tid = threadIdx.x;
    const int lane = tid & 63, w = tid >> 6;
    const int l31 = lane & 31, lh = lane >> 5;

    // ---- A: 32 rows (hi+lo), full K=256, in regs (MFMA B-operand) ----
    short8 ah[16], al[16];
    {
        const unsigned short* ph = khiB + (size_t)(rowbase + l31) * HDIM + lh * 8;
        const unsigned short* pl = kloB + (size_t)(rowbase + l31) * HDIM + lh * 8;
#pragma unroll
        for (int T = 0; T < 16; ++T) {
            ah[T] = *(const short8*)(ph + T * 16);
            al[T] = *(const short8*)(pl + T * 16);
        }
    }
#pragma unroll
    for (int T = 0; T < 16; ++T) {
        asm volatile("" : "+v"(ah[T]));
        asm volatile("" : "+v"(al[T]));
    }

    char* mybuf = smem + w * 12288;               // wave-private 3 x 4KB

    // ---- staging: chunk s = (cs, ks): cols [w*1024+cs*32, +32), K [ks*32, +32), hi+lo ----
    // lane=(c,sg): c=lane>>2 (16 cols/instr), sg=lane&3 (4 x 16B segs). Source seg
    // pre-swizzled sg ^ ((c>>1)&3) (involution, conflict-free on read side); LDS dest linear.
    const int sc = lane >> 2, sg = lane & 3;
    const int ssw = (sg ^ ((sc >> 1) & 3)) * 8;   // element offset of swizzled 16B seg
    auto stage = [&](int s) {
        const int cs2 = s >> 3, ks2 = s & 7;
        char* dst = mybuf + (s % 3) * 4096;
        const int c0 = w * 1024 + cs2 * 32;
#pragma unroll
        for (int p = 0; p < 2; ++p) {
            const unsigned short* pb = p ? kloB : khiB;
#pragma unroll
            for (int i = 0; i < 2; ++i) {
                const unsigned short* src = pb + (size_t)(c0 + i * 16 + sc) * HDIM + ks2 * 32 + ssw;
                __builtin_amdgcn_global_load_lds(
                    (const __attribute__((address_space(1))) void*)src,
                    (__attribute__((address_space(3))) void*)(dst + p * 2048 + i * 1024), 16, 0, 0);
            }
        }
    };

    stage(0);
    stage(1);

    // conflict-free read offsets (loop-invariant): slot = (kk*2+lh) ^ ((l31>>1)&3)
    const int key = (l31 >> 1) & 3;
    const int rb0 = l31 * 64 + ((lh ^ key) * 16);            // kk = 0
    const int rb1 = l31 * 64 + (((2 + lh) ^ key) * 16);      // kk = 1

    float tv[8]; int ti[8];
#pragma unroll
    for (int s = 0; s < 8; ++s) { tv[s] = -1e30f; ti[s] = 0x7fffffff; }

    for (int cs = 0; cs < 32; ++cs) {
        f32x16 acc;
#pragma unroll
        for (int r = 0; r < 16; ++r) acc[r] = 0.f;

#pragma unroll
        for (int ks = 0; ks < 8; ++ks) {
            const int s = cs * 8 + ks;
            // stage(s) landed: at step top issued stages are 0..s+1 -> allow 4 outstanding
            if (s < 255) asm volatile("s_waitcnt vmcnt(4)" ::: "memory");
            else         asm volatile("s_waitcnt vmcnt(0)" ::: "memory");

            const char* bufc = mybuf + (s % 3) * 4096;
            // issue this step's reads FIRST (stay in flight under lgkmcnt(4))
            short8 Bh0 = *(const short8*)(bufc + rb0);
            short8 Bl0 = *(const short8*)(bufc + 2048 + rb0);
            short8 Bh1 = *(const short8*)(bufc + rb1);
            short8 Bl1 = *(const short8*)(bufc + 2048 + rb1);
            // drain only the PREVIOUS step's reads before overwriting its buffer
            asm volatile("s_waitcnt lgkmcnt(4)" ::: "memory");
            if (s + 2 < 256) stage(s + 2);

            const int T0 = ks * 2, T1 = ks * 2 + 1;
            acc = __builtin_amdgcn_mfma_f32_32x32x16_bf16(Bh0, ah[T0], acc, 0, 0, 0);
            acc = __builtin_amdgcn_mfma_f32_32x32x16_bf16(Bh0, al[T0], acc, 0, 0, 0);
            acc = __builtin_amdgcn_mfma_f32_32x32x16_bf16(Bl0, ah[T0], acc, 0, 0, 0);
            acc = __builtin_amdgcn_mfma_f32_32x32x16_bf16(Bh1, ah[T1], acc, 0, 0, 0);
            acc = __builtin_amdgcn_mfma_f32_32x32x16_bf16(Bh1, al[T1], acc, 0, 0, 0);
            acc = __builtin_amdgcn_mfma_f32_32x32x16_bf16(Bl1, ah[T1], acc, 0, 0, 0);
        }

        // scan 16 lane-local sim values (ascending col; strict > = ref tie semantics)
        const int cbase = w * 1024 + cs * 32 + 4 * lh;
#pragma unroll
        for (int r = 0; r < 16; ++r) {
            float v = acc[r];
            int col = cbase + (r & 3) + 8 * (r >> 2);
            if (v > tv[7]) {
                tv[7] = v; ti[7] = col;
#pragma unroll
                for (int q = 7; q >= 1; --q) {
                    if (tv[q] > tv[q - 1]) {
                        float a0 = tv[q]; tv[q] = tv[q - 1]; tv[q - 1] = a0;
                        int   c0_ = ti[q]; ti[q] = ti[q - 1]; ti[q - 1] = c0_;
                    }
                }
            }
        }
    }

    // ---- merge 8 partial lists per row (4 waves x 2 lh), lexicographic ----
    __syncthreads();
    float* vbuf = (float*)smem;               // [32][66]
    int*   ibuf = (int*)(smem + 32 * 66 * 4);
    const int list = w * 2 + lh;
#pragma unroll
    for (int s = 0; s < 8; ++s) {
        vbuf[l31 * 66 + list * 8 + s] = tv[s];
        ibuf[l31 * 66 + list * 8 + s] = ti[s];
    }
    __syncthreads();
    if (tid < 32) {
        float fv[8]; int fi[8];
#pragma unroll
        for (int s = 0; s < 8; ++s) { fv[s] = -1e30f; fi[s] = 0x7fffffff; }
        for (int e = 0; e < 64; ++e) {
            float v = vbuf[tid * 66 + e];
            int  ix = ibuf[tid * 66 + e];
            bool ins = (v > fv[7]) || (v == fv[7] && ix < fi[7]);
            if (ins) {
                fv[7] = v; fi[7] = ix;
#pragma unroll
                for (int q = 7; q >= 1; --q) {
                    bool sw = (fv[q] > fv[q - 1]) || (fv[q] == fv[q - 1] && fi[q] < fi[q - 1]);
                    if (sw) {
                        float a0 = fv[q]; fv[q] = fv[q - 1]; fv[q - 1] = a0;
                        int   c0_ = fi[q]; fi[q] = fi[q - 1]; fi[q - 1] = c0_;
                    }
                }
            }
        }
        size_t basei = ((size_t)b * NN + rowbase + tid) * 8;
#pragma unroll
        for (int s = 0; s < 8; ++s) idxout[basei + s] = fi[s];
    }
}

// ---------------- keys projection GEMM + fused normalize -> khi/klo (bf16 planes) ----------------
__global__ __launch_bounds__(256, 2)
void gemm_keys(const float* __restrict__ A, const float* __restrict__ W,
               const float* __restrict__ bias,
               unsigned short* __restrict__ khi, unsigned short* __restrict__ klo) {
    __shared__ float As[32 * 132];
    int tid = threadIdx.x;
    size_t rowbase = (size_t)blockIdx.x * 32;
    for (int i = tid; i < 32 * 32; i += 256) {
        int r = i >> 5, q = i & 31;
        *(float4*)&As[r * 132 + q * 4] = *(const float4*)&A[(rowbase + r) * DDIM + q * 4];
    }
    __syncthreads();
    int rg = tid >> 5, cg = tid & 31;
    int r0 = rg * 4, c0 = cg * 8;
    float acc[4][8];
#pragma unroll
    for (int i = 0; i < 4; ++i)
#pragma unroll
        for (int j = 0; j < 8; ++j) acc[i][j] = 0.f;

#pragma unroll 2
    for (int k = 0; k < DDIM; k += 4) {
        float a[4][4];
#pragma unroll
        for (int i = 0; i < 4; ++i) {
            float4 t = *(const float4*)&As[(r0 + i) * 132 + k];
            a[i][0] = t.x; a[i][1] = t.y; a[i][2] = t.z; a[i][3] = t.w;
        }
#pragma unroll
        for (int kk = 0; kk < 4; ++kk) {
            float4 w0 = *(const float4*)&W[(size_t)(k + kk) * HDIM + c0];
            float4 w1 = *(const float4*)&W[(size_t)(k + kk) * HDIM + c0 + 4];
            float wv[8] = {w0.x, w0.y, w0.z, w0.w, w1.x, w1.y, w1.z, w1.w};
#pragma unroll
            for (int i = 0; i < 4; ++i)
#pragma unroll
                for (int j = 0; j < 8; ++j) acc[i][j] += a[i][kk] * wv[j];
        }
    }
    float4 bz0 = *(const float4*)&bias[c0];
    float4 bz1 = *(const float4*)&bias[c0 + 4];
    float bz[8] = {bz0.x, bz0.y, bz0.z, bz0.w, bz1.x, bz1.y, bz1.z, bz1.w};
#pragma unroll
    for (int i = 0; i < 4; ++i) {
        float vv[8];
        float ss = 0.f;
#pragma unroll
        for (int j = 0; j < 8; ++j) { vv[j] = acc[i][j] + bz[j]; ss += vv[j]*vv[j]; }
#pragma unroll
        for (int m = 16; m; m >>= 1) ss += __shfl_xor(ss, m);
        float sc = 1.0f / fmaxf(sqrtf(ss), 1e-12f);
        short8 hv, lv;
#pragma unroll
        for (int j = 0; j < 8; ++j) {
            float vn = vv[j] * sc;
            unsigned short h = f2bf(vn);
            hv[j] = (short)h;
            lv[j] = (short)f2bf(vn - bf2f(h));
        }
        *(short8*)&khi[(rowbase + r0 + i) * HDIM + c0] = hv;
        *(short8*)&klo[(rowbase + r0 + i) * HDIM + c0] = lv;
    }
}

// ---------------- agg projection GEMM: out = A(Rx128) @ W(128x256) + bias ----------------
__global__ __launch_bounds__(256, 2)
void gemm_d_h(const float* __restrict__ A, const float* __restrict__ W,
              const float* __restrict__ bias, float* __restrict__ out) {
    __shared__ float As[32 * 132];
    int tid = threadIdx.x;
    size_t rowbase = (size_t)blockIdx.x * 32;
    for (int i = tid; i < 32 * 32; i += 256) {
        int r = i >> 5, q = i & 31;
        *(float4*)&As[r * 132 + q * 4] = *(const float4*)&A[(rowbase + r) * DDIM + q * 4];
    }
    __syncthreads();
    int rg = tid >> 5, cg = tid & 31;
    int r0 = rg * 4, c0 = cg * 8;
    float acc[4][8];
#pragma unroll
    for (int i = 0; i < 4; ++i)
#pragma unroll
        for (int j = 0; j < 8; ++j) acc[i][j] = 0.f;

#pragma unroll 2
    for (int k = 0; k < DDIM; k += 4) {
        float a[4][4];
#pragma unroll
        for (int i = 0; i < 4; ++i) {
            float4 t = *(const float4*)&As[(r0 + i) * 132 + k];
            a[i][0] = t.x; a[i][1] = t.y; a[i][2] = t.z; a[i][3] = t.w;
        }
#pragma unroll
        for (int kk = 0; kk < 4; ++kk) {
            float4 w0 = *(const float4*)&W[(size_t)(k + kk) * HDIM + c0];
            float4 w1 = *(const float4*)&W[(size_t)(k + kk) * HDIM + c0 + 4];
            float wv[8] = {w0.x, w0.y, w0.z, w0.w, w1.x, w1.y, w1.z, w1.w};
#pragma unroll
            for (int i = 0; i < 4; ++i)
#pragma unroll
                for (int j = 0; j < 8; ++j) acc[i][j] += a[i][kk] * wv[j];
        }
    }
    float4 bz0 = *(const float4*)&bias[c0];
    float4 bz1 = *(const float4*)&bias[c0 + 4];
    float bz[8] = {bz0.x, bz0.y, bz0.z, bz0.w, bz1.x, bz1.y, bz1.z, bz1.w};
#pragma unroll
    for (int i = 0; i < 4; ++i) {
        float4 o0, o1;
        o0.x = acc[i][0] + bz[0]; o0.y = acc[i][1] + bz[1]; o0.z = acc[i][2] + bz[2]; o0.w = acc[i][3] + bz[3];
        o1.x = acc[i][4] + bz[4]; o1.y = acc[i][5] + bz[5]; o1.z = acc[i][6] + bz[6]; o1.w = acc[i][7] + bz[7];
        *(float4*)&out[(rowbase + r0 + i) * HDIM + c0] = o0;
        *(float4*)&out[(rowbase + r0 + i) * HDIM + c0 + 4] = o1;
    }
}

// ---------------- gather top-8 rows + mean, 2 rows / block ----------------
__global__ void gather_mean_kernel(const float* __restrict__ state, const int* __restrict__ idx,
                                   float* __restrict__ M) {
    __shared__ int ilds[16];
    int tid = threadIdx.x;
    int row0 = blockIdx.x * 2;
    if (tid < 16) ilds[tid] = idx[(size_t)row0 * 8 + tid];
    __syncthreads();
    int lr = tid >> 7, d = tid & 127;
    int grow = row0 + lr;
    int b = grow >> 12;
    const float* sb = state + (size_t)b * NN * DDIM;
    float acc = 0.f;
#pragma unroll
    for (int k = 0; k < 8; ++k) acc += sb[(size_t)ilds[lr * 8 + k] * DDIM + d];
    M[(size_t)grow * DDIM + d] = acc * 0.125f;
}

// ---------------- concat GEMM (K=384) + LayerNorm epilogue ----------------
__global__ __launch_bounds__(256, 2)
void gemm_ln(const float* __restrict__ state, const float* __restrict__ agg,
             const float* __restrict__ W1, const float* __restrict__ b1,
             const float* __restrict__ lng, const float* __restrict__ lnb,
             float* __restrict__ h) {
    __shared__ float As[32 * 388];
    int tid = threadIdx.x;
    size_t rowbase = (size_t)blockIdx.x * 32;
    for (int i = tid; i < 32 * 96; i += 256) {
        int r = i / 96, q = i % 96;
        float4 v;
        if (q < 32) v = *(const float4*)&state[(rowbase + r) * DDIM + q * 4];
        else        v = *(const float4*)&agg[(rowbase + r) * HDIM + (q - 32) * 4];
        *(float4*)&As[r * 388 + q * 4] = v;
    }
    __syncthreads();
    int rg = tid >> 5, cg = tid & 31;
    int r0 = rg * 4, c0 = cg * 8;
    float acc[4][8];
#pragma unroll
    for (int i = 0; i < 4; ++i)
#pragma unroll
        for (int j = 0; j < 8; ++j) acc[i][j] = 0.f;

#pragma unroll 2
    for (int k = 0; k < 384; k += 4) {
        float a[4][4];
#pragma unroll
        for (int i = 0; i < 4; ++i) {
            float4 t = *(const float4*)&As[(r0 + i) * 388 + k];
            a[i][0] = t.x; a[i][1] = t.y; a[i][2] = t.z; a[i][3] = t.w;
        }
#pragma unroll
        for (int kk = 0; kk < 4; ++kk) {
            float4 w0 = *(const float4*)&W1[(size_t)(k + kk) * HDIM + c0];
            float4 w1 = *(const float4*)&W1[(size_t)(k + kk) * HDIM + c0 + 4];
            float wv[8] = {w0.x, w0.y, w0.z, w0.w, w1.x, w1.y, w1.z, w1.w};
#pragma unroll
            for (int i = 0; i < 4; ++i)
#pragma unroll
                for (int j = 0; j < 8; ++j) acc[i][j] += a[i][kk] * wv[j];
        }
    }
    float4 b10 = *(const float4*)&b1[c0];
    float4 b11 = *(const float4*)&b1[c0 + 4];
    float bb[8] = {b10.x, b10.y, b10.z, b10.w, b11.x, b11.y, b11.z, b11.w};
    float4 g0 = *(const float4*)&lng[c0];
    float4 g1 = *(const float4*)&lng[c0 + 4];
    float lg[8] = {g0.x, g0.y, g0.z, g0.w, g1.x, g1.y, g1.z, g1.w};
    float4 e0 = *(const float4*)&lnb[c0];
    float4 e1 = *(const float4*)&lnb[c0 + 4];
    float lb[8] = {e0.x, e0.y, e0.z, e0.w, e1.x, e1.y, e1.z, e1.w};

#pragma unroll
    for (int i = 0; i < 4; ++i) {
        float s1 = 0.f, s2 = 0.f;
#pragma unroll
        for (int j = 0; j < 8; ++j) {
            acc[i][j] += bb[j];
            s1 += acc[i][j];
            s2 += acc[i][j] * acc[i][j];
        }
#pragma unroll
        for (int m = 16; m; m >>= 1) { s1 += __shfl_xor(s1, m); s2 += __shfl_xor(s2, m); }
        float mu = s1 * (1.0f / HDIM);
        float var = s2 * (1.0f / HDIM) - mu * mu;
        float inv = 1.0f / sqrtf(var + 1e-5f);
        float4 o0, o1;
        o0.x = (acc[i][0] - mu) * inv * lg[0] + lb[0];
        o0.y = (acc[i][1] - mu) * inv * lg[1] + lb[1];
        o0.z = (acc[i][2] - mu) * inv * lg[2] + lb[2];
        o0.w = (acc[i][3] - mu) * inv * lg[3] + lb[3];
        o1.x = (acc[i][4] - mu) * inv * lg[4] + lb[4];
        o1.y = (acc[i][5] - mu) * inv * lg[5] + lb[5];
        o1.z = (acc[i][6] - mu) * inv * lg[6] + lb[6];
        o1.w = (acc[i][7] - mu) * inv * lg[7] + lb[7];
        *(float4*)&h[(rowbase + r0 + i) * HDIM + c0] = o0;
        *(float4*)&h[(rowbase + r0 + i) * HDIM + c0 + 4] = o1;
    }
}

// ---------------- update GEMM: state += silu(h) @ W2 + b2 ----------------
__global__ __launch_bounds__(256, 2)
void gemm_upd(const float* __restrict__ h, const float* __restrict__ W2,
              const float* __restrict__ b2, float* __restrict__ state) {
    __shared__ float As[32 * 260];
    int tid = threadIdx.x;
    size_t rowbase = (size_t)blockIdx.x * 32;
    for (int i = tid; i < 32 * 64; i += 256) {
        int r = i >> 6, q = i & 63;
        float4 v = *(const float4*)&h[(rowbase + r) * HDIM + q * 4];
        v.x = v.x / (1.0f + expf(-v.x));
        v.y = v.y / (1.0f + expf(-v.y));
        v.z = v.z / (1.0f + expf(-v.z));
        v.w = v.w / (1.0f + expf(-v.w));
        *(float4*)&As[r * 260 + q * 4] = v;
    }
    __syncthreads();
    int rg = tid >> 4, cg = tid & 15;
    int r0 = rg * 2, c0 = cg * 8;
    float acc[2][8];
#pragma unroll
    for (int i = 0; i < 2; ++i)
#pragma unroll
        for (int j = 0; j < 8; ++j) acc[i][j] = 0.f;

#pragma unroll 2
    for (int k = 0; k < HDIM; k += 4) {
        float a[2][4];
#pragma unroll
        for (int i = 0; i < 2; ++i) {
            float4 t = *(const float4*)&As[(r0 + i) * 260 + k];
            a[i][0] = t.x; a[i][1] = t.y; a[i][2] = t.z; a[i][3] = t.w;
        }
#pragma unroll
        for (int kk = 0; kk < 4; ++kk) {
            float4 w0 = *(const float4*)&W2[(size_t)(k + kk) * DDIM + c0];
            float4 w1 = *(const float4*)&W2[(size_t)(k + kk) * DDIM + c0 + 4];
            float wv[8] = {w0.x, w0.y, w0.z, w0.w, w1.x, w1.y, w1.z, w1.w};
#pragma unroll
            for (int i = 0; i < 2; ++i)
#pragma unroll
                for (int j = 0; j < 8; ++j) acc[i][j] += a[i][kk] * wv[j];
        }
    }
    float4 bz0 = *(const float4*)&b2[c0];
    float4 bz1 = *(const float4*)&b2[c0 + 4];
    float bz[8] = {bz0.x, bz0.y, bz0.z, bz0.w, bz1.x, bz1.y, bz1.z, bz1.w};
#pragma unroll
    for (int i = 0; i < 2; ++i) {
        size_t off = (rowbase + r0 + i) * DDIM + c0;
        float4 s0 = *(const float4*)&state[off];
        float4 s1 = *(const float4*)&state[off + 4];
        s0.x += acc[i][0] + bz[0]; s0.y += acc[i][1] + bz[1];
        s0.z += acc[i][2] + bz[2]; s0.w += acc[i][3] + bz[3];
        s1.x += acc[i][4] + bz[4]; s1.y += acc[i][5] + bz[5];
        s1.z += acc[i][6] + bz[6]; s1.w += acc[i][7] + bz[7];
        *(float4*)&state[off] = s0;
        *(float4*)&state[off + 4] = s1;
    }
}

// ---------------- final: mean over N, then @ Wo + bo ----------------
__global__ void partial_mean_kernel(const float* __restrict__ state, float* __restrict__ partial) {
    int b = blockIdx.y, seg = blockIdx.x, tid = threadIdx.x;  // 128 threads
    const float* sp = state + ((size_t)b * NN + (size_t)seg * 128) * DDIM;
    float acc = 0.f;
    for (int i = 0; i < 128; ++i) acc += sp[(size_t)i * DDIM + tid];
    partial[((size_t)b * 32 + seg) * DDIM + tid] = acc;
}

__global__ void final_out_kernel(const float* __restrict__ partial, const float* __restrict__ Wo,
                                 const float* __restrict__ bo, float* __restrict__ out) {
    __shared__ float mean[BQ][DDIM];
    int tid = threadIdx.x;
    for (int o = tid; o < BQ * DDIM; o += 256) {
        int b = o >> 7, d = o & 127;
        float s = 0.f;
        for (int p = 0; p < 32; ++p) s += partial[((size_t)b * 32 + p) * DDIM + d];
        mean[b][d] = s * (1.0f / NN);
    }
    __syncthreads();
    for (int o = tid; o < BQ * DDIM; o += 256) {
        int b = o >> 7, c = o & 127;
        float acc = bo[c];
        for (int d = 0; d < DDIM; ++d) acc += mean[b][d] * Wo[d * DDIM + c];
        out[o] = acc;
    }
}

extern "C" void kernel_launch(void* const* d_in, const int* in_sizes, int n_in,
                              void* d_out, int out_size, void* d_ws, size_t ws_size,
                              hipStream_t stream) {
    const float* x   = (const float*)d_in[0];
    const float* Wn  = (const float*)d_in[1];
    const float* bn  = (const float*)d_in[2];
    const float* W1  = (const float*)d_in[3];
    const float* b1  = (const float*)d_in[4];
    const float* lng = (const float*)d_in[5];
    const float* lnb = (const float*)d_in[6];
    const float* W2  = (const float*)d_in[7];
    const float* b2  = (const float*)d_in[8];
    const float* Wo  = (const float*)d_in[9];
    const float* bo  = (const float*)d_in[10];
    float* out = (float*)d_out;

    float* ws      = (float*)d_ws;
    float* state   = ws;                                        // R*128 f32
    float* keysagg = state + (size_t)RTOT * DDIM;               // R*256 f32
    float* hbuf    = keysagg + (size_t)RTOT * HDIM;             // R*256 f32
    unsigned short* khi_b = (unsigned short*)hbuf;              // R*256 bf16
    unsigned short* klo_b = khi_b + (size_t)RTOT * HDIM;        // R*256 bf16
    float* Mbuf    = hbuf;                                      // R*128 f32 (after sim)
    float* partial = hbuf + (size_t)RTOT * HDIM;                // B*32*128
    int*   idxbuf  = (int*)(partial + (size_t)BQ * 32 * DDIM);  // R*8 ints

    hipMemcpyAsync(state, x, (size_t)RTOT * DDIM * sizeof(float),
                   hipMemcpyDeviceToDevice, stream);

    for (int step = 0; step < 3; ++step) {
        gemm_keys<<<RTOT / 32, 256, 0, stream>>>(state, Wn, bn, khi_b, klo_b);
        sim_topk_kernel<<<512, 256, 0, stream>>>(khi_b, klo_b, idxbuf);
        gather_mean_kernel<<<RTOT / 2, 256, 0, stream>>>(state, idxbuf, Mbuf);
        gemm_d_h<<<RTOT / 32, 256, 0, stream>>>(Mbuf, Wn, bn, keysagg);
        gemm_ln<<<RTOT / 32, 256, 0, stream>>>(state, keysagg, W1, b1, lng, lnb, hbuf);
        gemm_upd<<<RTOT / 32, 256, 0, stream>>>(hbuf, W2, b2, state);
    }
    partial_mean_kernel<<<dim3(32, BQ), 128, 0, stream>>>(state, partial);
    final_out_kernel<<<1, 256, 0, stream>>>(partial, Wo, bo, out);
}

// Round 10
// 857.750 us; speedup vs baseline: 5.0029x; 1.2258x over previous
//
#include <hip/hip_runtime.h>

#define DDIM 128
#define HDIM 256
#define BQ   4
#define NN   4096
#define RTOT (BQ*NN)

typedef short short8 __attribute__((ext_vector_type(8)));
typedef short short4v __attribute__((ext_vector_type(4)));
typedef float f32x16 __attribute__((ext_vector_type(16)));

__device__ inline unsigned short f2bf(float f) {
    unsigned int u = __float_as_uint(f);
    unsigned int r = (u + 0x7fffu + ((u >> 16) & 1u)) >> 16;
    return (unsigned short)r;
}
__device__ inline float bf2f(unsigned short h) {
    return __uint_as_float(((unsigned int)h) << 16);
}

#define MFMA32(a, b, c) __builtin_amdgcn_mfma_f32_32x32x16_bf16(a, b, c, 0, 0, 0)

// ---------------- weight packer: W(KxN fp32) -> bf16 hi/lo fragment-ordered ----------------
// frag (t,c): lane l holds 8 shorts = W[t*16 + (l>>5)*8 + j][c*32 + (l&31)].
// pack index (t*(N/32)+c)*64 + l  (== blockIdx.x*64 + l). Run once per launch.
__global__ void pack_w_kernel(const float* __restrict__ W, int N,
                              unsigned short* __restrict__ ph, unsigned short* __restrict__ pl) {
    int l = threadIdx.x, l31 = l & 31, lh = l >> 5;
    int nt = N >> 5;
    int t = blockIdx.x / nt, c = blockIdx.x % nt;
    short8 hv, lv;
#pragma unroll
    for (int j = 0; j < 8; ++j) {
        float f = W[(size_t)(t * 16 + lh * 8 + j) * N + c * 32 + l31];
        unsigned short h = f2bf(f);
        hv[j] = (short)h;
        lv[j] = (short)f2bf(f - bf2f(h));
    }
    *(short8*)(ph + (size_t)(blockIdx.x * 64 + l) * 8) = hv;
    *(short8*)(pl + (size_t)(blockIdx.x * 64 + l) * 8) = lv;
}

// ---------------- fused sim (unchanged from round 9: 204 us, working) ----------------
__global__ __launch_bounds__(256, 2)
void sim_topk_kernel(const unsigned short* __restrict__ khi,
                     const unsigned short* __restrict__ klo,
                     int* __restrict__ idxout) {
    __shared__ __align__(16) char smem[4 * 3 * 4096];

    const int id = blockIdx.x;
    const int xcd = id & 7;
    const int b = xcd >> 1;
    const int j = ((id >> 3) << 1) | (xcd & 1);
    const int rowbase = j * 32;
    const unsigned short* khiB = khi + (size_t)b * NN * HDIM;
    const unsigned short* kloB = klo + (size_t)b * NN * HDIM;

    const int tid = threadIdx.x;
    const int lane = tid & 63, w = tid >> 6;
    const int l31 = lane & 31, lh = lane >> 5;

    short8 ah[16], al[16];
    {
        const unsigned short* ph = khiB + (size_t)(rowbase + l31) * HDIM + lh * 8;
        const unsigned short* pl = kloB + (size_t)(rowbase + l31) * HDIM + lh * 8;
#pragma unroll
        for (int T = 0; T < 16; ++T) {
            ah[T] = *(const short8*)(ph + T * 16);
            al[T] = *(const short8*)(pl + T * 16);
        }
    }
#pragma unroll
    for (int T = 0; T < 16; ++T) {
        asm volatile("" : "+v"(ah[T]));
        asm volatile("" : "+v"(al[T]));
    }

    char* mybuf = smem + w * 12288;

    const int sc = lane >> 2, sg = lane & 3;
    const int ssw = (sg ^ ((sc >> 1) & 3)) * 8;
    auto stage = [&](int s) {
        const int cs2 = s >> 3, ks2 = s & 7;
        char* dst = mybuf + (s % 3) * 4096;
        const int c0 = w * 1024 + cs2 * 32;
#pragma unroll
        for (int p = 0; p < 2; ++p) {
            const unsigned short* pb = p ? kloB : khiB;
#pragma unroll
            for (int i = 0; i < 2; ++i) {
                const unsigned short* src = pb + (size_t)(c0 + i * 16 + sc) * HDIM + ks2 * 32 + ssw;
                __builtin_amdgcn_global_load_lds(
                    (const __attribute__((address_space(1))) void*)src,
                    (__attribute__((address_space(3))) void*)(dst + p * 2048 + i * 1024), 16, 0, 0);
            }
        }
    };

    stage(0);
    stage(1);

    const int key = (l31 >> 1) & 3;
    const int rb0 = l31 * 64 + ((lh ^ key) * 16);
    const int rb1 = l31 * 64 + (((2 + lh) ^ key) * 16);

    float tv[8]; int ti[8];
#pragma unroll
    for (int s = 0; s < 8; ++s) { tv[s] = -1e30f; ti[s] = 0x7fffffff; }

    for (int cs = 0; cs < 32; ++cs) {
        f32x16 acc;
#pragma unroll
        for (int r = 0; r < 16; ++r) acc[r] = 0.f;

#pragma unroll
        for (int ks = 0; ks < 8; ++ks) {
            const int s = cs * 8 + ks;
            if (s < 255) asm volatile("s_waitcnt vmcnt(4)" ::: "memory");
            else         asm volatile("s_waitcnt vmcnt(0)" ::: "memory");

            const char* bufc = mybuf + (s % 3) * 4096;
            short8 Bh0 = *(const short8*)(bufc + rb0);
            short8 Bl0 = *(const short8*)(bufc + 2048 + rb0);
            short8 Bh1 = *(const short8*)(bufc + rb1);
            short8 Bl1 = *(const short8*)(bufc + 2048 + rb1);
            asm volatile("s_waitcnt lgkmcnt(4)" ::: "memory");
            if (s + 2 < 256) stage(s + 2);

            const int T0 = ks * 2, T1 = ks * 2 + 1;
            acc = MFMA32(Bh0, ah[T0], acc);
            acc = MFMA32(Bh0, al[T0], acc);
            acc = MFMA32(Bl0, ah[T0], acc);
            acc = MFMA32(Bh1, ah[T1], acc);
            acc = MFMA32(Bh1, al[T1], acc);
            acc = MFMA32(Bl1, ah[T1], acc);
        }

        const int cbase = w * 1024 + cs * 32 + 4 * lh;
#pragma unroll
        for (int r = 0; r < 16; ++r) {
            float v = acc[r];
            int col = cbase + (r & 3) + 8 * (r >> 2);
            if (v > tv[7]) {
                tv[7] = v; ti[7] = col;
#pragma unroll
                for (int q = 7; q >= 1; --q) {
                    if (tv[q] > tv[q - 1]) {
                        float a0 = tv[q]; tv[q] = tv[q - 1]; tv[q - 1] = a0;
                        int   c0_ = ti[q]; ti[q] = ti[q - 1]; ti[q - 1] = c0_;
                    }
                }
            }
        }
    }

    __syncthreads();
    float* vbuf = (float*)smem;
    int*   ibuf = (int*)(smem + 32 * 66 * 4);
    const int list = w * 2 + lh;
#pragma unroll
    for (int s = 0; s < 8; ++s) {
        vbuf[l31 * 66 + list * 8 + s] = tv[s];
        ibuf[l31 * 66 + list * 8 + s] = ti[s];
    }
    __syncthreads();
    if (tid < 32) {
        float fv[8]; int fi[8];
#pragma unroll
        for (int s = 0; s < 8; ++s) { fv[s] = -1e30f; fi[s] = 0x7fffffff; }
        for (int e = 0; e < 64; ++e) {
            float v = vbuf[tid * 66 + e];
            int  ix = ibuf[tid * 66 + e];
            bool ins = (v > fv[7]) || (v == fv[7] && ix < fi[7]);
            if (ins) {
                fv[7] = v; fi[7] = ix;
#pragma unroll
                for (int q = 7; q >= 1; --q) {
                    bool sw = (fv[q] > fv[q - 1]) || (fv[q] == fv[q - 1] && fi[q] < fi[q - 1]);
                    if (sw) {
                        float a0 = fv[q]; fv[q] = fv[q - 1]; fv[q - 1] = a0;
                        int   c0_ = fi[q]; fi[q] = fi[q - 1]; fi[q - 1] = c0_;
                    }
                }
            }
        }
        size_t basei = ((size_t)b * NN + rowbase + tid) * 8;
#pragma unroll
        for (int s = 0; s < 8; ++s) idxout[basei + s] = fi[s];
    }
}

// ---------------- MFMA keys GEMM + normalize -> khi/klo ----------------
// grid R/64, block 256 = 4 waves (rw = row half, cw = col half). Wave: 32 rows x 128 cols.
// D layout (verified via sim): lane l31 -> row, reg r -> col (r&3)+8*(r>>2)+4*lh (+32*tile).
__global__ __launch_bounds__(256, 2)
void gemm_keys_mfma(const float* __restrict__ A,
                    const unsigned short* __restrict__ wh, const unsigned short* __restrict__ wl,
                    const float* __restrict__ bias,
                    unsigned short* __restrict__ khi, unsigned short* __restrict__ klo) {
    __shared__ float ssqbuf[2][32][2];
    const int tid = threadIdx.x, lane = tid & 63, w = tid >> 6;
    const int l31 = lane & 31, lh = lane >> 5;
    const int rw = w & 1, cw = w >> 1;
    const int row = blockIdx.x * 64 + rw * 32 + l31;

    short8 ahi[8], alo[8];
    const float* ap = A + (size_t)row * DDIM + lh * 8;
#pragma unroll
    for (int T = 0; T < 8; ++T) {
        float4 f0 = *(const float4*)(ap + T * 16);
        float4 f1 = *(const float4*)(ap + T * 16 + 4);
        float ff[8] = {f0.x, f0.y, f0.z, f0.w, f1.x, f1.y, f1.z, f1.w};
#pragma unroll
        for (int j2 = 0; j2 < 8; ++j2) {
            unsigned short h = f2bf(ff[j2]);
            ahi[T][j2] = (short)h;
            alo[T][j2] = (short)f2bf(ff[j2] - bf2f(h));
        }
    }

    f32x16 acc[4];
#pragma unroll
    for (int ct = 0; ct < 4; ++ct)
#pragma unroll
        for (int r = 0; r < 16; ++r) acc[ct][r] = 0.f;

#pragma unroll
    for (int T = 0; T < 8; ++T) {
#pragma unroll
        for (int ct = 0; ct < 4; ++ct) {
            const size_t pi = (size_t)((T * 8 + cw * 4 + ct) * 64 + lane) * 8;
            short8 bh = *(const short8*)(wh + pi);
            short8 bl = *(const short8*)(wl + pi);
            acc[ct] = MFMA32(bh, ahi[T], acc[ct]);
            acc[ct] = MFMA32(bl, ahi[T], acc[ct]);
            acc[ct] = MFMA32(bh, alo[T], acc[ct]);
        }
    }

    float ss = 0.f;
#pragma unroll
    for (int ct = 0; ct < 4; ++ct)
#pragma unroll
        for (int g = 0; g < 4; ++g) {
            const int c0 = cw * 128 + ct * 32 + g * 8 + lh * 4;
            float4 bz = *(const float4*)(bias + c0);
            float bzf[4] = {bz.x, bz.y, bz.z, bz.w};
#pragma unroll
            for (int j2 = 0; j2 < 4; ++j2) {
                acc[ct][g * 4 + j2] += bzf[j2];
                ss += acc[ct][g * 4 + j2] * acc[ct][g * 4 + j2];
            }
        }
    ss += __shfl_xor(ss, 32);
    if (lh == 0) ssqbuf[rw][l31][cw] = ss;
    __syncthreads();
    float sstot = ssqbuf[rw][l31][0] + ssqbuf[rw][l31][1];
    float scn = 1.0f / fmaxf(sqrtf(sstot), 1e-12f);

#pragma unroll
    for (int ct = 0; ct < 4; ++ct)
#pragma unroll
        for (int g = 0; g < 4; ++g) {
            const int c0 = cw * 128 + ct * 32 + g * 8 + lh * 4;
            short4v hv, lv;
#pragma unroll
            for (int j2 = 0; j2 < 4; ++j2) {
                float vn = acc[ct][g * 4 + j2] * scn;
                unsigned short h = f2bf(vn);
                hv[j2] = (short)h;
                lv[j2] = (short)f2bf(vn - bf2f(h));
            }
            *(short4v*)(khi + (size_t)row * HDIM + c0) = hv;
            *(short4v*)(klo + (size_t)row * HDIM + c0) = lv;
        }
}

// ---------------- MFMA agg GEMM: Mbuf(Rx128) @ Wn + bn -> split-bf16 agghi/agglo ----------------
__global__ __launch_bounds__(256, 2)
void gemm_agg_mfma(const float* __restrict__ A,
                   const unsigned short* __restrict__ wh, const unsigned short* __restrict__ wl,
                   const float* __restrict__ bias,
                   unsigned short* __restrict__ oh, unsigned short* __restrict__ ol) {
    const int tid = threadIdx.x, lane = tid & 63, w = tid >> 6;
    const int l31 = lane & 31, lh = lane >> 5;
    const int rw = w & 1, cw = w >> 1;
    const int row = blockIdx.x * 64 + rw * 32 + l31;

    short8 ahi[8], alo[8];
    const float* ap = A + (size_t)row * DDIM + lh * 8;
#pragma unroll
    for (int T = 0; T < 8; ++T) {
        float4 f0 = *(const float4*)(ap + T * 16);
        float4 f1 = *(const float4*)(ap + T * 16 + 4);
        float ff[8] = {f0.x, f0.y, f0.z, f0.w, f1.x, f1.y, f1.z, f1.w};
#pragma unroll
        for (int j2 = 0; j2 < 8; ++j2) {
            unsigned short h = f2bf(ff[j2]);
            ahi[T][j2] = (short)h;
            alo[T][j2] = (short)f2bf(ff[j2] - bf2f(h));
        }
    }

    f32x16 acc[4];
#pragma unroll
    for (int ct = 0; ct < 4; ++ct)
#pragma unroll
        for (int r = 0; r < 16; ++r) acc[ct][r] = 0.f;

#pragma unroll
    for (int T = 0; T < 8; ++T) {
#pragma unroll
        for (int ct = 0; ct < 4; ++ct) {
            const size_t pi = (size_t)((T * 8 + cw * 4 + ct) * 64 + lane) * 8;
            short8 bh = *(const short8*)(wh + pi);
            short8 bl = *(const short8*)(wl + pi);
            acc[ct] = MFMA32(bh, ahi[T], acc[ct]);
            acc[ct] = MFMA32(bl, ahi[T], acc[ct]);
            acc[ct] = MFMA32(bh, alo[T], acc[ct]);
        }
    }

#pragma unroll
    for (int ct = 0; ct < 4; ++ct)
#pragma unroll
        for (int g = 0; g < 4; ++g) {
            const int c0 = cw * 128 + ct * 32 + g * 8 + lh * 4;
            float4 bz = *(const float4*)(bias + c0);
            float bzf[4] = {bz.x, bz.y, bz.z, bz.w};
            short4v hv, lv;
#pragma unroll
            for (int j2 = 0; j2 < 4; ++j2) {
                float vn = acc[ct][g * 4 + j2] + bzf[j2];
                unsigned short h = f2bf(vn);
                hv[j2] = (short)h;
                lv[j2] = (short)f2bf(vn - bf2f(h));
            }
            *(short4v*)(oh + (size_t)row * HDIM + c0) = hv;
            *(short4v*)(ol + (size_t)row * HDIM + c0) = lv;
        }
}

// ---------------- MFMA concat GEMM (K=384) + LN + silu -> split-bf16 g ----------------
__global__ __launch_bounds__(256, 2)
void gemm_ln_mfma(const float* __restrict__ state,
                  const unsigned short* __restrict__ agh, const unsigned short* __restrict__ agl,
                  const unsigned short* __restrict__ wh, const unsigned short* __restrict__ wl,
                  const float* __restrict__ b1, const float* __restrict__ lng,
                  const float* __restrict__ lnb,
                  unsigned short* __restrict__ gh, unsigned short* __restrict__ gl) {
    __shared__ float s1buf[2][32][2], s2buf[2][32][2];
    const int tid = threadIdx.x, lane = tid & 63, w = tid >> 6;
    const int l31 = lane & 31, lh = lane >> 5;
    const int rw = w & 1, cw = w >> 1;
    const int row = blockIdx.x * 64 + rw * 32 + l31;

    f32x16 acc[4];
#pragma unroll
    for (int ct = 0; ct < 4; ++ct)
#pragma unroll
        for (int r = 0; r < 16; ++r) acc[ct][r] = 0.f;

    short8 ahi[8], alo[8];
    // kc = 0: state (fp32 -> split)
    {
        const float* ap = state + (size_t)row * DDIM + lh * 8;
#pragma unroll
        for (int T = 0; T < 8; ++T) {
            float4 f0 = *(const float4*)(ap + T * 16);
            float4 f1 = *(const float4*)(ap + T * 16 + 4);
            float ff[8] = {f0.x, f0.y, f0.z, f0.w, f1.x, f1.y, f1.z, f1.w};
#pragma unroll
            for (int j2 = 0; j2 < 8; ++j2) {
                unsigned short h = f2bf(ff[j2]);
                ahi[T][j2] = (short)h;
                alo[T][j2] = (short)f2bf(ff[j2] - bf2f(h));
            }
        }
#pragma unroll
        for (int T = 0; T < 8; ++T)
#pragma unroll
            for (int ct = 0; ct < 4; ++ct) {
                const size_t pi = (size_t)((T * 8 + cw * 4 + ct) * 64 + lane) * 8;
                short8 bh = *(const short8*)(wh + pi);
                short8 bl = *(const short8*)(wl + pi);
                acc[ct] = MFMA32(bh, ahi[T], acc[ct]);
                acc[ct] = MFMA32(bl, ahi[T], acc[ct]);
                acc[ct] = MFMA32(bh, alo[T], acc[ct]);
            }
    }
    // kc = 1,2: agg (already split bf16)
#pragma unroll
    for (int kc = 1; kc < 3; ++kc) {
#pragma unroll
        for (int T = 0; T < 8; ++T) {
            ahi[T] = *(const short8*)(agh + (size_t)row * HDIM + (kc - 1) * 128 + T * 16 + lh * 8);
            alo[T] = *(const short8*)(agl + (size_t)row * HDIM + (kc - 1) * 128 + T * 16 + lh * 8);
        }
#pragma unroll
        for (int T = 0; T < 8; ++T)
#pragma unroll
            for (int ct = 0; ct < 4; ++ct) {
                const size_t pi = (size_t)(((kc * 8 + T) * 8 + cw * 4 + ct) * 64 + lane) * 8;
                short8 bh = *(const short8*)(wh + pi);
                short8 bl = *(const short8*)(wl + pi);
                acc[ct] = MFMA32(bh, ahi[T], acc[ct]);
                acc[ct] = MFMA32(bl, ahi[T], acc[ct]);
                acc[ct] = MFMA32(bh, alo[T], acc[ct]);
            }
    }

    // + b1, LN stats over 256 cols
    float s1 = 0.f, s2 = 0.f;
#pragma unroll
    for (int ct = 0; ct < 4; ++ct)
#pragma unroll
        for (int g = 0; g < 4; ++g) {
            const int c0 = cw * 128 + ct * 32 + g * 8 + lh * 4;
            float4 bz = *(const float4*)(b1 + c0);
            float bzf[4] = {bz.x, bz.y, bz.z, bz.w};
#pragma unroll
            for (int j2 = 0; j2 < 4; ++j2) {
                acc[ct][g * 4 + j2] += bzf[j2];
                s1 += acc[ct][g * 4 + j2];
                s2 += acc[ct][g * 4 + j2] * acc[ct][g * 4 + j2];
            }
        }
    s1 += __shfl_xor(s1, 32);
    s2 += __shfl_xor(s2, 32);
    if (lh == 0) { s1buf[rw][l31][cw] = s1; s2buf[rw][l31][cw] = s2; }
    __syncthreads();
    float s1t = s1buf[rw][l31][0] + s1buf[rw][l31][1];
    float s2t = s2buf[rw][l31][0] + s2buf[rw][l31][1];
    float mu = s1t * (1.0f / HDIM);
    float var = s2t * (1.0f / HDIM) - mu * mu;
    float inv = 1.0f / sqrtf(var + 1e-5f);

#pragma unroll
    for (int ct = 0; ct < 4; ++ct)
#pragma unroll
        for (int g = 0; g < 4; ++g) {
            const int c0 = cw * 128 + ct * 32 + g * 8 + lh * 4;
            float4 gg = *(const float4*)(lng + c0);
            float4 bb = *(const float4*)(lnb + c0);
            float ggf[4] = {gg.x, gg.y, gg.z, gg.w};
            float bbf[4] = {bb.x, bb.y, bb.z, bb.w};
            short4v hv, lv;
#pragma unroll
            for (int j2 = 0; j2 < 4; ++j2) {
                float hval = (acc[ct][g * 4 + j2] - mu) * inv * ggf[j2] + bbf[j2];
                float gval = hval / (1.0f + expf(-hval));   // silu
                unsigned short h = f2bf(gval);
                hv[j2] = (short)h;
                lv[j2] = (short)f2bf(gval - bf2f(h));
            }
            *(short4v*)(gh + (size_t)row * HDIM + c0) = hv;
            *(short4v*)(gl + (size_t)row * HDIM + c0) = lv;
        }
}

// ---------------- MFMA update GEMM: state += g(Rx256,split) @ W2 + b2 ----------------
__global__ __launch_bounds__(256, 2)
void gemm_upd_mfma(const unsigned short* __restrict__ gh, const unsigned short* __restrict__ gl,
                   const unsigned short* __restrict__ wh, const unsigned short* __restrict__ wl,
                   const float* __restrict__ b2, float* __restrict__ state) {
    const int tid = threadIdx.x, lane = tid & 63, w = tid >> 6;
    const int l31 = lane & 31, lh = lane >> 5;
    const int rw = w & 1, cw = w >> 1;
    const int row = blockIdx.x * 64 + rw * 32 + l31;

    f32x16 acc[2];
#pragma unroll
    for (int ct = 0; ct < 2; ++ct)
#pragma unroll
        for (int r = 0; r < 16; ++r) acc[ct][r] = 0.f;

    short8 ahi[8], alo[8];
#pragma unroll
    for (int kc = 0; kc < 2; ++kc) {
#pragma unroll
        for (int T = 0; T < 8; ++T) {
            ahi[T] = *(const short8*)(gh + (size_t)row * HDIM + kc * 128 + T * 16 + lh * 8);
            alo[T] = *(const short8*)(gl + (size_t)row * HDIM + kc * 128 + T * 16 + lh * 8);
        }
#pragma unroll
        for (int T = 0; T < 8; ++T)
#pragma unroll
            for (int ct = 0; ct < 2; ++ct) {
                const size_t pi = (size_t)(((kc * 8 + T) * 4 + cw * 2 + ct) * 64 + lane) * 8;
                short8 bh = *(const short8*)(wh + pi);
                short8 bl = *(const short8*)(wl + pi);
                acc[ct] = MFMA32(bh, ahi[T], acc[ct]);
                acc[ct] = MFMA32(bl, ahi[T], acc[ct]);
                acc[ct] = MFMA32(bh, alo[T], acc[ct]);
            }
    }

#pragma unroll
    for (int ct = 0; ct < 2; ++ct)
#pragma unroll
        for (int g = 0; g < 4; ++g) {
            const int c0 = cw * 64 + ct * 32 + g * 8 + lh * 4;
            float4 bz = *(const float4*)(b2 + c0);
            float bzf[4] = {bz.x, bz.y, bz.z, bz.w};
            float4* sp = (float4*)(state + (size_t)row * DDIM + c0);
            float4 sv = *sp;
            float svf[4] = {sv.x, sv.y, sv.z, sv.w};
#pragma unroll
            for (int j2 = 0; j2 < 4; ++j2) svf[j2] += acc[ct][g * 4 + j2] + bzf[j2];
            sv.x = svf[0]; sv.y = svf[1]; sv.z = svf[2]; sv.w = svf[3];
            *sp = sv;
        }
}

// ---------------- gather top-8 rows + mean, 2 rows / block (unchanged) ----------------
__global__ void gather_mean_kernel(const float* __restrict__ state, const int* __restrict__ idx,
                                   float* __restrict__ M) {
    __shared__ int ilds[16];
    int tid = threadIdx.x;
    int row0 = blockIdx.x * 2;
    if (tid < 16) ilds[tid] = idx[(size_t)row0 * 8 + tid];
    __syncthreads();
    int lr = tid >> 7, d = tid & 127;
    int grow = row0 + lr;
    int b = grow >> 12;
    const float* sb = state + (size_t)b * NN * DDIM;
    float acc = 0.f;
#pragma unroll
    for (int k = 0; k < 8; ++k) acc += sb[(size_t)ilds[lr * 8 + k] * DDIM + d];
    M[(size_t)grow * DDIM + d] = acc * 0.125f;
}

// ---------------- final: mean over N, then @ Wo + bo (unchanged) ----------------
__global__ void partial_mean_kernel(const float* __restrict__ state, float* __restrict__ partial) {
    int b = blockIdx.y, seg = blockIdx.x, tid = threadIdx.x;
    const float* sp = state + ((size_t)b * NN + (size_t)seg * 128) * DDIM;
    float acc = 0.f;
    for (int i = 0; i < 128; ++i) acc += sp[(size_t)i * DDIM + tid];
    partial[((size_t)b * 32 + seg) * DDIM + tid] = acc;
}

__global__ void final_out_kernel(const float* __restrict__ partial, const float* __restrict__ Wo,
                                 const float* __restrict__ bo, float* __restrict__ out) {
    __shared__ float mean[BQ][DDIM];
    int tid = threadIdx.x;
    for (int o = tid; o < BQ * DDIM; o += 256) {
        int b = o >> 7, d = o & 127;
        float s = 0.f;
        for (int p = 0; p < 32; ++p) s += partial[((size_t)b * 32 + p) * DDIM + d];
        mean[b][d] = s * (1.0f / NN);
    }
    __syncthreads();
    for (int o = tid; o < BQ * DDIM; o += 256) {
        int b = o >> 7, c = o & 127;
        float acc = bo[c];
        for (int d = 0; d < DDIM; ++d) acc += mean[b][d] * Wo[d * DDIM + c];
        out[o] = acc;
    }
}

extern "C" void kernel_launch(void* const* d_in, const int* in_sizes, int n_in,
                              void* d_out, int out_size, void* d_ws, size_t ws_size,
                              hipStream_t stream) {
    const float* x   = (const float*)d_in[0];
    const float* Wn  = (const float*)d_in[1];
    const float* bn  = (const float*)d_in[2];
    const float* W1  = (const float*)d_in[3];
    const float* b1  = (const float*)d_in[4];
    const float* lng = (const float*)d_in[5];
    const float* lnb = (const float*)d_in[6];
    const float* W2  = (const float*)d_in[7];
    const float* b2  = (const float*)d_in[8];
    const float* Wo  = (const float*)d_in[9];
    const float* bo  = (const float*)d_in[10];
    float* out = (float*)d_out;

    // ws layout:
    // state (R*128 f32) | agghi/agglo (R*256 u16 x2, = old keysagg 16MB) |
    // khi/klo (R*256 u16 x2, 16MB; khi reused as Mbuf f32 R*128 after sim; khi/klo reused
    // as ghi/glo after agg) | partial | idx | packed weights (~0.77MB)
    float* ws    = (float*)d_ws;
    float* state = ws;                                             // 8 MB
    unsigned short* agghi = (unsigned short*)(state + (size_t)RTOT * DDIM);
    unsigned short* agglo = agghi + (size_t)RTOT * HDIM;
    unsigned short* khi_b = agglo + (size_t)RTOT * HDIM;
    unsigned short* klo_b = khi_b + (size_t)RTOT * HDIM;
    float* Mbuf = (float*)khi_b;                                   // alias (khi dead after sim)
    unsigned short* ghi = khi_b;                                   // alias (Mbuf dead after agg)
    unsigned short* glo = klo_b;                                   // alias (klo dead after sim)
    float* partial = (float*)(klo_b + (size_t)RTOT * HDIM);        // BQ*32*128
    int*   idxbuf  = (int*)(partial + (size_t)BQ * 32 * DDIM);     // R*8
    unsigned short* wnh = (unsigned short*)(idxbuf + (size_t)RTOT * 8);
    unsigned short* wnl = wnh + 128 * 256;
    unsigned short* w1h = wnl + 128 * 256;
    unsigned short* w1l = w1h + 384 * 256;
    unsigned short* w2h = w1l + 384 * 256;
    unsigned short* w2l = w2h + 256 * 128;

    hipMemcpyAsync(state, x, (size_t)RTOT * DDIM * sizeof(float),
                   hipMemcpyDeviceToDevice, stream);

    pack_w_kernel<<<(128 / 16) * (256 / 32), 64, 0, stream>>>(Wn, 256, wnh, wnl);
    pack_w_kernel<<<(384 / 16) * (256 / 32), 64, 0, stream>>>(W1, 256, w1h, w1l);
    pack_w_kernel<<<(256 / 16) * (128 / 32), 64, 0, stream>>>(W2, 128, w2h, w2l);

    for (int step = 0; step < 3; ++step) {
        gemm_keys_mfma<<<RTOT / 64, 256, 0, stream>>>(state, wnh, wnl, bn, khi_b, klo_b);
        sim_topk_kernel<<<512, 256, 0, stream>>>(khi_b, klo_b, idxbuf);
        gather_mean_kernel<<<RTOT / 2, 256, 0, stream>>>(state, idxbuf, Mbuf);
        gemm_agg_mfma<<<RTOT / 64, 256, 0, stream>>>(Mbuf, wnh, wnl, bn, agghi, agglo);
        gemm_ln_mfma<<<RTOT / 64, 256, 0, stream>>>(state, agghi, agglo, w1h, w1l,
                                                    b1, lng, lnb, ghi, glo);
        gemm_upd_mfma<<<RTOT / 64, 256, 0, stream>>>(ghi, glo, w2h, w2l, b2, state);
    }
    partial_mean_kernel<<<dim3(32, BQ), 128, 0, stream>>>(state, partial);
    final_out_kernel<<<1, 256, 0, stream>>>(partial, Wo, bo, out);
}

// Round 11
// 832.236 us; speedup vs baseline: 5.1563x; 1.0307x over previous
//
#include <hip/hip_runtime.h>

#define DDIM 128
#define HDIM 256
#define BQ   4
#define NN   4096
#define RTOT (BQ*NN)

typedef short short8 __attribute__((ext_vector_type(8)));
typedef short short4v __attribute__((ext_vector_type(4)));
typedef float f32x16 __attribute__((ext_vector_type(16)));

__device__ inline unsigned short f2bf(float f) {
    unsigned int u = __float_as_uint(f);
    unsigned int r = (u + 0x7fffu + ((u >> 16) & 1u)) >> 16;
    return (unsigned short)r;
}
__device__ inline float bf2f(unsigned short h) {
    return __uint_as_float(((unsigned int)h) << 16);
}

#define MFMA32(a, b, c) __builtin_amdgcn_mfma_f32_32x32x16_bf16(a, b, c, 0, 0, 0)

// ---------------- weight packer: W(KxN fp32) -> bf16 hi/lo fragment-ordered ----------------
__global__ void pack_w_kernel(const float* __restrict__ W, int N,
                              unsigned short* __restrict__ ph, unsigned short* __restrict__ pl) {
    int l = threadIdx.x, l31 = l & 31, lh = l >> 5;
    int nt = N >> 5;
    int t = blockIdx.x / nt, c = blockIdx.x % nt;
    short8 hv, lv;
#pragma unroll
    for (int j = 0; j < 8; ++j) {
        float f = W[(size_t)(t * 16 + lh * 8 + j) * N + c * 32 + l31];
        unsigned short h = f2bf(f);
        hv[j] = (short)h;
        lv[j] = (short)f2bf(f - bf2f(h));
    }
    *(short8*)(ph + (size_t)(blockIdx.x * 64 + l) * 8) = hv;
    *(short8*)(pl + (size_t)(blockIdx.x * 64 + l) * 8) = lv;
}

// ---------------- fused sim + top-8: round-10 structure, prefetch depth 2 -> 3 ----------------
// 4 buffers/wave (16KB), prefetch s+3, vmcnt(8): ~300cy slack covers L2 DMA latency
// (round-10 depth-2 gave only ~200cy -> per-step residual stall). Protocol otherwise identical.
__global__ __launch_bounds__(256, 2)
void sim_topk_kernel(const unsigned short* __restrict__ khi,
                     const unsigned short* __restrict__ klo,
                     int* __restrict__ idxout) {
    __shared__ __align__(16) char smem[4 * 4 * 4096];   // 4 waves x 4 bufs x 4KB = 64 KB

    const int id = blockIdx.x;
    const int xcd = id & 7;
    const int b = xcd >> 1;
    const int j = ((id >> 3) << 1) | (xcd & 1);
    const int rowbase = j * 32;
    const unsigned short* khiB = khi + (size_t)b * NN * HDIM;
    const unsigned short* kloB = klo + (size_t)b * NN * HDIM;

    const int tid = threadIdx.x;
    const int lane = tid & 63, w = tid >> 6;
    const int l31 = lane & 31, lh = lane >> 5;

    short8 ah[16], al[16];
    {
        const unsigned short* ph = khiB + (size_t)(rowbase + l31) * HDIM + lh * 8;
        const unsigned short* pl = kloB + (size_t)(rowbase + l31) * HDIM + lh * 8;
#pragma unroll
        for (int T = 0; T < 16; ++T) {
            ah[T] = *(const short8*)(ph + T * 16);
            al[T] = *(const short8*)(pl + T * 16);
        }
    }
#pragma unroll
    for (int T = 0; T < 16; ++T) {
        asm volatile("" : "+v"(ah[T]));
        asm volatile("" : "+v"(al[T]));
    }

    char* mybuf = smem + w * 16384;               // wave-private 4 x 4KB

    const int sc = lane >> 2, sg = lane & 3;
    const int ssw = (sg ^ ((sc >> 1) & 3)) * 8;
    auto stage = [&](int s) {
        const int cs2 = s >> 3, ks2 = s & 7;
        char* dst = mybuf + (s % 4) * 4096;
        const int c0 = w * 1024 + cs2 * 32;
#pragma unroll
        for (int p = 0; p < 2; ++p) {
            const unsigned short* pb = p ? kloB : khiB;
#pragma unroll
            for (int i = 0; i < 2; ++i) {
                const unsigned short* src = pb + (size_t)(c0 + i * 16 + sc) * HDIM + ks2 * 32 + ssw;
                __builtin_amdgcn_global_load_lds(
                    (const __attribute__((address_space(1))) void*)src,
                    (__attribute__((address_space(3))) void*)(dst + p * 2048 + i * 1024), 16, 0, 0);
            }
        }
    };

    stage(0);
    stage(1);
    stage(2);

    const int key = (l31 >> 1) & 3;
    const int rb0 = l31 * 64 + ((lh ^ key) * 16);
    const int rb1 = l31 * 64 + (((2 + lh) ^ key) * 16);

    float tv[8]; int ti[8];
#pragma unroll
    for (int s = 0; s < 8; ++s) { tv[s] = -1e30f; ti[s] = 0x7fffffff; }

    for (int cs = 0; cs < 32; ++cs) {
        f32x16 acc;
#pragma unroll
        for (int r = 0; r < 16; ++r) acc[r] = 0.f;

#pragma unroll
        for (int ks = 0; ks < 8; ++ks) {
            const int s = cs * 8 + ks;
            // need stage(s) landed; stages s+1,s+2 may be outstanding (8 loads)
            if (s < 254)       asm volatile("s_waitcnt vmcnt(8)" ::: "memory");
            else if (s == 254) asm volatile("s_waitcnt vmcnt(4)" ::: "memory");
            else               asm volatile("s_waitcnt vmcnt(0)" ::: "memory");

            const char* bufc = mybuf + (s % 4) * 4096;
            short8 Bh0 = *(const short8*)(bufc + rb0);
            short8 Bl0 = *(const short8*)(bufc + 2048 + rb0);
            short8 Bh1 = *(const short8*)(bufc + rb1);
            short8 Bl1 = *(const short8*)(bufc + 2048 + rb1);
            // drain the PREVIOUS step's reads before overwriting its buffer (mod-4 distinct)
            asm volatile("s_waitcnt lgkmcnt(4)" ::: "memory");
            if (s + 3 < 256) stage(s + 3);

            const int T0 = ks * 2, T1 = ks * 2 + 1;
            acc = MFMA32(Bh0, ah[T0], acc);
            acc = MFMA32(Bh0, al[T0], acc);
            acc = MFMA32(Bl0, ah[T0], acc);
            acc = MFMA32(Bh1, ah[T1], acc);
            acc = MFMA32(Bh1, al[T1], acc);
            acc = MFMA32(Bl1, ah[T1], acc);
        }

        const int cbase = w * 1024 + cs * 32 + 4 * lh;
#pragma unroll
        for (int r = 0; r < 16; ++r) {
            float v = acc[r];
            int col = cbase + (r & 3) + 8 * (r >> 2);
            if (v > tv[7]) {
                tv[7] = v; ti[7] = col;
#pragma unroll
                for (int q = 7; q >= 1; --q) {
                    if (tv[q] > tv[q - 1]) {
                        float a0 = tv[q]; tv[q] = tv[q - 1]; tv[q - 1] = a0;
                        int   c0_ = ti[q]; ti[q] = ti[q - 1]; ti[q - 1] = c0_;
                    }
                }
            }
        }
    }

    __syncthreads();
    float* vbuf = (float*)smem;
    int*   ibuf = (int*)(smem + 32 * 66 * 4);
    const int list = w * 2 + lh;
#pragma unroll
    for (int s = 0; s < 8; ++s) {
        vbuf[l31 * 66 + list * 8 + s] = tv[s];
        ibuf[l31 * 66 + list * 8 + s] = ti[s];
    }
    __syncthreads();
    if (tid < 32) {
        float fv[8]; int fi[8];
#pragma unroll
        for (int s = 0; s < 8; ++s) { fv[s] = -1e30f; fi[s] = 0x7fffffff; }
        for (int e = 0; e < 64; ++e) {
            float v = vbuf[tid * 66 + e];
            int  ix = ibuf[tid * 66 + e];
            bool ins = (v > fv[7]) || (v == fv[7] && ix < fi[7]);
            if (ins) {
                fv[7] = v; fi[7] = ix;
#pragma unroll
                for (int q = 7; q >= 1; --q) {
                    bool sw = (fv[q] > fv[q - 1]) || (fv[q] == fv[q - 1] && fi[q] < fi[q - 1]);
                    if (sw) {
                        float a0 = fv[q]; fv[q] = fv[q - 1]; fv[q - 1] = a0;
                        int   c0_ = fi[q]; fi[q] = fi[q - 1]; fi[q - 1] = c0_;
                    }
                }
            }
        }
        size_t basei = ((size_t)b * NN + rowbase + tid) * 8;
#pragma unroll
        for (int s = 0; s < 8; ++s) idxout[basei + s] = fi[s];
    }
}

// ---------------- MFMA keys GEMM + normalize -> khi/klo (unchanged, working) ----------------
__global__ __launch_bounds__(256, 2)
void gemm_keys_mfma(const float* __restrict__ A,
                    const unsigned short* __restrict__ wh, const unsigned short* __restrict__ wl,
                    const float* __restrict__ bias,
                    unsigned short* __restrict__ khi, unsigned short* __restrict__ klo) {
    __shared__ float ssqbuf[2][32][2];
    const int tid = threadIdx.x, lane = tid & 63, w = tid >> 6;
    const int l31 = lane & 31, lh = lane >> 5;
    const int rw = w & 1, cw = w >> 1;
    const int row = blockIdx.x * 64 + rw * 32 + l31;

    short8 ahi[8], alo[8];
    const float* ap = A + (size_t)row * DDIM + lh * 8;
#pragma unroll
    for (int T = 0; T < 8; ++T) {
        float4 f0 = *(const float4*)(ap + T * 16);
        float4 f1 = *(const float4*)(ap + T * 16 + 4);
        float ff[8] = {f0.x, f0.y, f0.z, f0.w, f1.x, f1.y, f1.z, f1.w};
#pragma unroll
        for (int j2 = 0; j2 < 8; ++j2) {
            unsigned short h = f2bf(ff[j2]);
            ahi[T][j2] = (short)h;
            alo[T][j2] = (short)f2bf(ff[j2] - bf2f(h));
        }
    }

    f32x16 acc[4];
#pragma unroll
    for (int ct = 0; ct < 4; ++ct)
#pragma unroll
        for (int r = 0; r < 16; ++r) acc[ct][r] = 0.f;

#pragma unroll
    for (int T = 0; T < 8; ++T) {
#pragma unroll
        for (int ct = 0; ct < 4; ++ct) {
            const size_t pi = (size_t)((T * 8 + cw * 4 + ct) * 64 + lane) * 8;
            short8 bh = *(const short8*)(wh + pi);
            short8 bl = *(const short8*)(wl + pi);
            acc[ct] = MFMA32(bh, ahi[T], acc[ct]);
            acc[ct] = MFMA32(bl, ahi[T], acc[ct]);
            acc[ct] = MFMA32(bh, alo[T], acc[ct]);
        }
    }

    float ss = 0.f;
#pragma unroll
    for (int ct = 0; ct < 4; ++ct)
#pragma unroll
        for (int g = 0; g < 4; ++g) {
            const int c0 = cw * 128 + ct * 32 + g * 8 + lh * 4;
            float4 bz = *(const float4*)(bias + c0);
            float bzf[4] = {bz.x, bz.y, bz.z, bz.w};
#pragma unroll
            for (int j2 = 0; j2 < 4; ++j2) {
                acc[ct][g * 4 + j2] += bzf[j2];
                ss += acc[ct][g * 4 + j2] * acc[ct][g * 4 + j2];
            }
        }
    ss += __shfl_xor(ss, 32);
    if (lh == 0) ssqbuf[rw][l31][cw] = ss;
    __syncthreads();
    float sstot = ssqbuf[rw][l31][0] + ssqbuf[rw][l31][1];
    float scn = 1.0f / fmaxf(sqrtf(sstot), 1e-12f);

#pragma unroll
    for (int ct = 0; ct < 4; ++ct)
#pragma unroll
        for (int g = 0; g < 4; ++g) {
            const int c0 = cw * 128 + ct * 32 + g * 8 + lh * 4;
            short4v hv, lv;
#pragma unroll
            for (int j2 = 0; j2 < 4; ++j2) {
                float vn = acc[ct][g * 4 + j2] * scn;
                unsigned short h = f2bf(vn);
                hv[j2] = (short)h;
                lv[j2] = (short)f2bf(vn - bf2f(h));
            }
            *(short4v*)(khi + (size_t)row * HDIM + c0) = hv;
            *(short4v*)(klo + (size_t)row * HDIM + c0) = lv;
        }
}

// ---------------- MFMA agg GEMM (unchanged) ----------------
__global__ __launch_bounds__(256, 2)
void gemm_agg_mfma(const float* __restrict__ A,
                   const unsigned short* __restrict__ wh, const unsigned short* __restrict__ wl,
                   const float* __restrict__ bias,
                   unsigned short* __restrict__ oh, unsigned short* __restrict__ ol) {
    const int tid = threadIdx.x, lane = tid & 63, w = tid >> 6;
    const int l31 = lane & 31, lh = lane >> 5;
    const int rw = w & 1, cw = w >> 1;
    const int row = blockIdx.x * 64 + rw * 32 + l31;

    short8 ahi[8], alo[8];
    const float* ap = A + (size_t)row * DDIM + lh * 8;
#pragma unroll
    for (int T = 0; T < 8; ++T) {
        float4 f0 = *(const float4*)(ap + T * 16);
        float4 f1 = *(const float4*)(ap + T * 16 + 4);
        float ff[8] = {f0.x, f0.y, f0.z, f0.w, f1.x, f1.y, f1.z, f1.w};
#pragma unroll
        for (int j2 = 0; j2 < 8; ++j2) {
            unsigned short h = f2bf(ff[j2]);
            ahi[T][j2] = (short)h;
            alo[T][j2] = (short)f2bf(ff[j2] - bf2f(h));
        }
    }

    f32x16 acc[4];
#pragma unroll
    for (int ct = 0; ct < 4; ++ct)
#pragma unroll
        for (int r = 0; r < 16; ++r) acc[ct][r] = 0.f;

#pragma unroll
    for (int T = 0; T < 8; ++T) {
#pragma unroll
        for (int ct = 0; ct < 4; ++ct) {
            const size_t pi = (size_t)((T * 8 + cw * 4 + ct) * 64 + lane) * 8;
            short8 bh = *(const short8*)(wh + pi);
            short8 bl = *(const short8*)(wl + pi);
            acc[ct] = MFMA32(bh, ahi[T], acc[ct]);
            acc[ct] = MFMA32(bl, ahi[T], acc[ct]);
            acc[ct] = MFMA32(bh, alo[T], acc[ct]);
        }
    }

#pragma unroll
    for (int ct = 0; ct < 4; ++ct)
#pragma unroll
        for (int g = 0; g < 4; ++g) {
            const int c0 = cw * 128 + ct * 32 + g * 8 + lh * 4;
            float4 bz = *(const float4*)(bias + c0);
            float bzf[4] = {bz.x, bz.y, bz.z, bz.w};
            short4v hv, lv;
#pragma unroll
            for (int j2 = 0; j2 < 4; ++j2) {
                float vn = acc[ct][g * 4 + j2] + bzf[j2];
                unsigned short h = f2bf(vn);
                hv[j2] = (short)h;
                lv[j2] = (short)f2bf(vn - bf2f(h));
            }
            *(short4v*)(oh + (size_t)row * HDIM + c0) = hv;
            *(short4v*)(ol + (size_t)row * HDIM + c0) = lv;
        }
}

// ---------------- MFMA concat GEMM (K=384) + LN + silu (unchanged) ----------------
__global__ __launch_bounds__(256, 2)
void gemm_ln_mfma(const float* __restrict__ state,
                  const unsigned short* __restrict__ agh, const unsigned short* __restrict__ agl,
                  const unsigned short* __restrict__ wh, const unsigned short* __restrict__ wl,
                  const float* __restrict__ b1, const float* __restrict__ lng,
                  const float* __restrict__ lnb,
                  unsigned short* __restrict__ gh, unsigned short* __restrict__ gl) {
    __shared__ float s1buf[2][32][2], s2buf[2][32][2];
    const int tid = threadIdx.x, lane = tid & 63, w = tid >> 6;
    const int l31 = lane & 31, lh = lane >> 5;
    const int rw = w & 1, cw = w >> 1;
    const int row = blockIdx.x * 64 + rw * 32 + l31;

    f32x16 acc[4];
#pragma unroll
    for (int ct = 0; ct < 4; ++ct)
#pragma unroll
        for (int r = 0; r < 16; ++r) acc[ct][r] = 0.f;

    short8 ahi[8], alo[8];
    {
        const float* ap = state + (size_t)row * DDIM + lh * 8;
#pragma unroll
        for (int T = 0; T < 8; ++T) {
            float4 f0 = *(const float4*)(ap + T * 16);
            float4 f1 = *(const float4*)(ap + T * 16 + 4);
            float ff[8] = {f0.x, f0.y, f0.z, f0.w, f1.x, f1.y, f1.z, f1.w};
#pragma unroll
            for (int j2 = 0; j2 < 8; ++j2) {
                unsigned short h = f2bf(ff[j2]);
                ahi[T][j2] = (short)h;
                alo[T][j2] = (short)f2bf(ff[j2] - bf2f(h));
            }
        }
#pragma unroll
        for (int T = 0; T < 8; ++T)
#pragma unroll
            for (int ct = 0; ct < 4; ++ct) {
                const size_t pi = (size_t)((T * 8 + cw * 4 + ct) * 64 + lane) * 8;
                short8 bh = *(const short8*)(wh + pi);
                short8 bl = *(const short8*)(wl + pi);
                acc[ct] = MFMA32(bh, ahi[T], acc[ct]);
                acc[ct] = MFMA32(bl, ahi[T], acc[ct]);
                acc[ct] = MFMA32(bh, alo[T], acc[ct]);
            }
    }
#pragma unroll
    for (int kc = 1; kc < 3; ++kc) {
#pragma unroll
        for (int T = 0; T < 8; ++T) {
            ahi[T] = *(const short8*)(agh + (size_t)row * HDIM + (kc - 1) * 128 + T * 16 + lh * 8);
            alo[T] = *(const short8*)(agl + (size_t)row * HDIM + (kc - 1) * 128 + T * 16 + lh * 8);
        }
#pragma unroll
        for (int T = 0; T < 8; ++T)
#pragma unroll
            for (int ct = 0; ct < 4; ++ct) {
                const size_t pi = (size_t)(((kc * 8 + T) * 8 + cw * 4 + ct) * 64 + lane) * 8;
                short8 bh = *(const short8*)(wh + pi);
                short8 bl = *(const short8*)(wl + pi);
                acc[ct] = MFMA32(bh, ahi[T], acc[ct]);
                acc[ct] = MFMA32(bl, ahi[T], acc[ct]);
                acc[ct] = MFMA32(bh, alo[T], acc[ct]);
            }
    }

    float s1 = 0.f, s2 = 0.f;
#pragma unroll
    for (int ct = 0; ct < 4; ++ct)
#pragma unroll
        for (int g = 0; g < 4; ++g) {
            const int c0 = cw * 128 + ct * 32 + g * 8 + lh * 4;
            float4 bz = *(const float4*)(b1 + c0);
            float bzf[4] = {bz.x, bz.y, bz.z, bz.w};
#pragma unroll
            for (int j2 = 0; j2 < 4; ++j2) {
                acc[ct][g * 4 + j2] += bzf[j2];
                s1 += acc[ct][g * 4 + j2];
                s2 += acc[ct][g * 4 + j2] * acc[ct][g * 4 + j2];
            }
        }
    s1 += __shfl_xor(s1, 32);
    s2 += __shfl_xor(s2, 32);
    if (lh == 0) { s1buf[rw][l31][cw] = s1; s2buf[rw][l31][cw] = s2; }
    __syncthreads();
    float s1t = s1buf[rw][l31][0] + s1buf[rw][l31][1];
    float s2t = s2buf[rw][l31][0] + s2buf[rw][l31][1];
    float mu = s1t * (1.0f / HDIM);
    float var = s2t * (1.0f / HDIM) - mu * mu;
    float inv = 1.0f / sqrtf(var + 1e-5f);

#pragma unroll
    for (int ct = 0; ct < 4; ++ct)
#pragma unroll
        for (int g = 0; g < 4; ++g) {
            const int c0 = cw * 128 + ct * 32 + g * 8 + lh * 4;
            float4 gg = *(const float4*)(lng + c0);
            float4 bb = *(const float4*)(lnb + c0);
            float ggf[4] = {gg.x, gg.y, gg.z, gg.w};
            float bbf[4] = {bb.x, bb.y, bb.z, bb.w};
            short4v hv, lv;
#pragma unroll
            for (int j2 = 0; j2 < 4; ++j2) {
                float hval = (acc[ct][g * 4 + j2] - mu) * inv * ggf[j2] + bbf[j2];
                float gval = hval / (1.0f + expf(-hval));
                unsigned short h = f2bf(gval);
                hv[j2] = (short)h;
                lv[j2] = (short)f2bf(gval - bf2f(h));
            }
            *(short4v*)(gh + (size_t)row * HDIM + c0) = hv;
            *(short4v*)(gl + (size_t)row * HDIM + c0) = lv;
        }
}

// ---------------- MFMA update GEMM (unchanged) ----------------
__global__ __launch_bounds__(256, 2)
void gemm_upd_mfma(const unsigned short* __restrict__ gh, const unsigned short* __restrict__ gl,
                   const unsigned short* __restrict__ wh, const unsigned short* __restrict__ wl,
                   const float* __restrict__ b2, float* __restrict__ state) {
    const int tid = threadIdx.x, lane = tid & 63, w = tid >> 6;
    const int l31 = lane & 31, lh = lane >> 5;
    const int rw = w & 1, cw = w >> 1;
    const int row = blockIdx.x * 64 + rw * 32 + l31;

    f32x16 acc[2];
#pragma unroll
    for (int ct = 0; ct < 2; ++ct)
#pragma unroll
        for (int r = 0; r < 16; ++r) acc[ct][r] = 0.f;

    short8 ahi[8], alo[8];
#pragma unroll
    for (int kc = 0; kc < 2; ++kc) {
#pragma unroll
        for (int T = 0; T < 8; ++T) {
            ahi[T] = *(const short8*)(gh + (size_t)row * HDIM + kc * 128 + T * 16 + lh * 8);
            alo[T] = *(const short8*)(gl + (size_t)row * HDIM + kc * 128 + T * 16 + lh * 8);
        }
#pragma unroll
        for (int T = 0; T < 8; ++T)
#pragma unroll
            for (int ct = 0; ct < 2; ++ct) {
                const size_t pi = (size_t)(((kc * 8 + T) * 4 + cw * 2 + ct) * 64 + lane) * 8;
                short8 bh = *(const short8*)(wh + pi);
                short8 bl = *(const short8*)(wl + pi);
                acc[ct] = MFMA32(bh, ahi[T], acc[ct]);
                acc[ct] = MFMA32(bl, ahi[T], acc[ct]);
                acc[ct] = MFMA32(bh, alo[T], acc[ct]);
            }
    }

#pragma unroll
    for (int ct = 0; ct < 2; ++ct)
#pragma unroll
        for (int g = 0; g < 4; ++g) {
            const int c0 = cw * 64 + ct * 32 + g * 8 + lh * 4;
            float4 bz = *(const float4*)(b2 + c0);
            float bzf[4] = {bz.x, bz.y, bz.z, bz.w};
            float4* sp = (float4*)(state + (size_t)row * DDIM + c0);
            float4 sv = *sp;
            float svf[4] = {sv.x, sv.y, sv.z, sv.w};
#pragma unroll
            for (int j2 = 0; j2 < 4; ++j2) svf[j2] += acc[ct][g * 4 + j2] + bzf[j2];
            sv.x = svf[0]; sv.y = svf[1]; sv.z = svf[2]; sv.w = svf[3];
            *sp = sv;
        }
}

// ---------------- gather / final (unchanged) ----------------
__global__ void gather_mean_kernel(const float* __restrict__ state, const int* __restrict__ idx,
                                   float* __restrict__ M) {
    __shared__ int ilds[16];
    int tid = threadIdx.x;
    int row0 = blockIdx.x * 2;
    if (tid < 16) ilds[tid] = idx[(size_t)row0 * 8 + tid];
    __syncthreads();
    int lr = tid >> 7, d = tid & 127;
    int grow = row0 + lr;
    int b = grow >> 12;
    const float* sb = state + (size_t)b * NN * DDIM;
    float acc = 0.f;
#pragma unroll
    for (int k = 0; k < 8; ++k) acc += sb[(size_t)ilds[lr * 8 + k] * DDIM + d];
    M[(size_t)grow * DDIM + d] = acc * 0.125f;
}

__global__ void partial_mean_kernel(const float* __restrict__ state, float* __restrict__ partial) {
    int b = blockIdx.y, seg = blockIdx.x, tid = threadIdx.x;
    const float* sp = state + ((size_t)b * NN + (size_t)seg * 128) * DDIM;
    float acc = 0.f;
    for (int i = 0; i < 128; ++i) acc += sp[(size_t)i * DDIM + tid];
    partial[((size_t)b * 32 + seg) * DDIM + tid] = acc;
}

__global__ void final_out_kernel(const float* __restrict__ partial, const float* __restrict__ Wo,
                                 const float* __restrict__ bo, float* __restrict__ out) {
    __shared__ float mean[BQ][DDIM];
    int tid = threadIdx.x;
    for (int o = tid; o < BQ * DDIM; o += 256) {
        int b = o >> 7, d = o & 127;
        float s = 0.f;
        for (int p = 0; p < 32; ++p) s += partial[((size_t)b * 32 + p) * DDIM + d];
        mean[b][d] = s * (1.0f / NN);
    }
    __syncthreads();
    for (int o = tid; o < BQ * DDIM; o += 256) {
        int b = o >> 7, c = o & 127;
        float acc = bo[c];
        for (int d = 0; d < DDIM; ++d) acc += mean[b][d] * Wo[d * DDIM + c];
        out[o] = acc;
    }
}

extern "C" void kernel_launch(void* const* d_in, const int* in_sizes, int n_in,
                              void* d_out, int out_size, void* d_ws, size_t ws_size,
                              hipStream_t stream) {
    const float* x   = (const float*)d_in[0];
    const float* Wn  = (const float*)d_in[1];
    const float* bn  = (const float*)d_in[2];
    const float* W1  = (const float*)d_in[3];
    const float* b1  = (const float*)d_in[4];
    const float* lng = (const float*)d_in[5];
    const float* lnb = (const float*)d_in[6];
    const float* W2  = (const float*)d_in[7];
    const float* b2  = (const float*)d_in[8];
    const float* Wo  = (const float*)d_in[9];
    const float* bo  = (const float*)d_in[10];
    float* out = (float*)d_out;

    float* ws    = (float*)d_ws;
    float* state = ws;
    unsigned short* agghi = (unsigned short*)(state + (size_t)RTOT * DDIM);
    unsigned short* agglo = agghi + (size_t)RTOT * HDIM;
    unsigned short* khi_b = agglo + (size_t)RTOT * HDIM;
    unsigned short* klo_b = khi_b + (size_t)RTOT * HDIM;
    float* Mbuf = (float*)khi_b;
    unsigned short* ghi = khi_b;
    unsigned short* glo = klo_b;
    float* partial = (float*)(klo_b + (size_t)RTOT * HDIM);
    int*   idxbuf  = (int*)(partial + (size_t)BQ * 32 * DDIM);
    unsigned short* wnh = (unsigned short*)(idxbuf + (size_t)RTOT * 8);
    unsigned short* wnl = wnh + 128 * 256;
    unsigned short* w1h = wnl + 128 * 256;
    unsigned short* w1l = w1h + 384 * 256;
    unsigned short* w2h = w1l + 384 * 256;
    unsigned short* w2l = w2h + 256 * 128;

    hipMemcpyAsync(state, x, (size_t)RTOT * DDIM * sizeof(float),
                   hipMemcpyDeviceToDevice, stream);

    pack_w_kernel<<<(128 / 16) * (256 / 32), 64, 0, stream>>>(Wn, 256, wnh, wnl);
    pack_w_kernel<<<(384 / 16) * (256 / 32), 64, 0, stream>>>(W1, 256, w1h, w1l);
    pack_w_kernel<<<(256 / 16) * (128 / 32), 64, 0, stream>>>(W2, 128, w2h, w2l);

    for (int step = 0; step < 3; ++step) {
        gemm_keys_mfma<<<RTOT / 64, 256, 0, stream>>>(state, wnh, wnl, bn, khi_b, klo_b);
        sim_topk_kernel<<<512, 256, 0, stream>>>(khi_b, klo_b, idxbuf);
        gather_mean_kernel<<<RTOT / 2, 256, 0, stream>>>(state, idxbuf, Mbuf);
        gemm_agg_mfma<<<RTOT / 64, 256, 0, stream>>>(Mbuf, wnh, wnl, bn, agghi, agglo);
        gemm_ln_mfma<<<RTOT / 64, 256, 0, stream>>>(state, agghi, agglo, w1h, w1l,
                                                    b1, lng, lnb, ghi, glo);
        gemm_upd_mfma<<<RTOT / 64, 256, 0, stream>>>(ghi, glo, w2h, w2l, b2, state);
    }
    partial_mean_kernel<<<dim3(32, BQ), 128, 0, stream>>>(state, partial);
    final_out_kernel<<<1, 256, 0, stream>>>(partial, Wo, bo, out);
}